// Round 9
// baseline (220.607 us; speedup 1.0000x reference)
//
#include <hip/hip_runtime.h>
#include <hip/hip_bf16.h>

// GCN via bucketed-CSR gather (no global fine-grain atomics), bf16-compressed
// gather operands, fused gather+MFMA layer-1:
//   xnb[i] = bf16(x[i]*dinv[i])
//   (fused) aggb row in LDS = bf16(dinv[d]*(xnb[d] + sum xnb[s])); h1b =
//           bf16(relu(LDSrow @ W1 + b1)) via v_mfma_f32_16x16x32_bf16
//   ts = bf16((h1b @ W2) * dinv[row])                            (fp32 acc)
//   h2[d] = dinv[d]*(ts[d] + sum_{s in N(d)} ts[s])              (fp32 accum)
//   out = log_softmax(segment_mean(h2) + b2)
// CSR build (2 kernels): fixed-stride bucket regions (8192 edges/bucket) ->
// partition -> per-bucket LDS counting sort emits offs/deg/dinv/srcs + xnb.

#define THREADS 256
#define NPB 512        // nodes per bucket (shift 9)
#define BSTRIDE 8192   // fixed edge capacity per bucket region
#define CH 8192        // edges per partition block
#define G1ROWS 256     // nodes per fused gather+gemm1 block

typedef __attribute__((ext_vector_type(8))) short bf16x8;
typedef __attribute__((ext_vector_type(4))) float f32x4;

__device__ __forceinline__ float bfu_lo(unsigned int u) {
    union { unsigned int i; float f; } v; v.i = u << 16; return v.f;
}
__device__ __forceinline__ float bfu_hi(unsigned int u) {
    union { unsigned int i; float f; } v; v.i = u & 0xffff0000u; return v.f;
}
__device__ __forceinline__ unsigned short f2bf(float f) {
    union { float f; unsigned int i; } v; v.f = f;
    unsigned int r = v.i + 0x7fff + ((v.i >> 16) & 1);  // RNE
    return (unsigned short)(r >> 16);
}
__device__ __forceinline__ unsigned int packbf(float lo, float hi) {
    return (unsigned int)f2bf(lo) | ((unsigned int)f2bf(hi) << 16);
}
__device__ __forceinline__ void unpack8(uint4 u, float* f) {
    f[0] = bfu_lo(u.x); f[1] = bfu_hi(u.x);
    f[2] = bfu_lo(u.y); f[3] = bfu_hi(u.y);
    f[4] = bfu_lo(u.z); f[5] = bfu_hi(u.z);
    f[6] = bfu_lo(u.w); f[7] = bfu_hi(u.w);
}

// Partition edges into fixed-stride bucket regions of ebuf as (src,dst) int2.
// LDS hist -> one reservation atomic per (block,bucket) -> LDS-cursor placement.
__global__ __launch_bounds__(THREADS) void k_partition(const int* __restrict__ src,
                                                       const int* __restrict__ dst,
                                                       int* __restrict__ bucketCursor,
                                                       int2* __restrict__ ebuf, int E) {
    __shared__ int h[256];
    __shared__ int base[256];
    __shared__ int cnt[256];
    h[threadIdx.x] = 0;
    cnt[threadIdx.x] = 0;
    __syncthreads();
    int b0 = blockIdx.x * CH;
    for (int k = 0; k < CH; k += THREADS) {
        int e = b0 + k + threadIdx.x;
        if (e < E) atomicAdd(&h[dst[e] >> 9], 1);
    }
    __syncthreads();
    if (h[threadIdx.x])
        base[threadIdx.x] = threadIdx.x * BSTRIDE + atomicAdd(&bucketCursor[threadIdx.x], h[threadIdx.x]);
    __syncthreads();
    for (int k = 0; k < CH; k += THREADS) {
        int e = b0 + k + threadIdx.x;
        if (e < E) {
            int s = src[e], d = dst[e];
            int b = d >> 9;
            int i = base[b] + atomicAdd(&cnt[b], 1);
            ebuf[i] = make_int2(s, d);
        }
    }
}

// One block per bucket: LDS counting sort -> offs/deg/dinv/srcs, then fused
// xnb emission (xnb[i] = bf16(x[i]*dinv[i])) for the bucket's 512 nodes.
__global__ __launch_bounds__(THREADS) void k_bucket_csr(const int2* __restrict__ ebuf,
                                                        const int* __restrict__ bucketCursor,
                                                        const float* __restrict__ x,
                                                        int* __restrict__ offs,
                                                        int* __restrict__ deg,
                                                        int* __restrict__ srcs,
                                                        float* __restrict__ dinv,
                                                        uint4* __restrict__ xnb,
                                                        int n) {
    __shared__ int c[NPB];
    __shared__ int cur[NPB];
    __shared__ float dloc[NPB];
    __shared__ int sh[THREADS];
    int b = blockIdx.x;
    int nbase = b * NPB;
    int w0 = b * BSTRIDE;
    int cnt_b = bucketCursor[b];
    c[threadIdx.x] = 0;
    c[threadIdx.x + 256] = 0;
    __syncthreads();
    for (int i = w0 + threadIdx.x; i < w0 + cnt_b; i += THREADS)
        atomicAdd(&c[ebuf[i].y - nbase], 1);
    __syncthreads();
    int c0 = c[2 * threadIdx.x], c1 = c[2 * threadIdx.x + 1];
    int s = c0 + c1;
    sh[threadIdx.x] = s;
    __syncthreads();
    for (int step = 1; step < THREADS; step <<= 1) {
        int t = (threadIdx.x >= step) ? sh[threadIdx.x - step] : 0;
        __syncthreads();
        sh[threadIdx.x] += t;
        __syncthreads();
    }
    int excl = sh[threadIdx.x] - s;
    int node0 = nbase + 2 * threadIdx.x;
    float d0 = rsqrtf((float)(c0 + 1));
    float d1 = rsqrtf((float)(c1 + 1));
    dloc[2 * threadIdx.x] = d0;
    dloc[2 * threadIdx.x + 1] = d1;
    if (node0 < n) {
        offs[node0] = w0 + excl;
        deg[node0] = c0;
        dinv[node0] = d0;
    }
    if (node0 + 1 < n) {
        offs[node0 + 1] = w0 + excl + c0;
        deg[node0 + 1] = c1;
        dinv[node0 + 1] = d1;
    }
    cur[2 * threadIdx.x] = excl;
    cur[2 * threadIdx.x + 1] = excl + c0;
    __syncthreads();
    for (int i = w0 + threadIdx.x; i < w0 + cnt_b; i += THREADS) {
        int2 e = ebuf[i];
        int pos = w0 + atomicAdd(&cur[e.y - nbase], 1);
        srcs[pos] = e.x;
    }
    // fused xnb: 8 uint4-chunks per node, 512 nodes, 16 iters per thread
    const float4* X4 = (const float4*)x;
    for (int i = threadIdx.x; i < NPB * 8; i += THREADS) {
        int ln = i >> 3;
        int node = nbase + ln;
        if (node >= n) break;  // nodes ascend with i; all later also >= n
        int q = i & 7;
        float dd = dloc[ln];
        float4 a = X4[(size_t)node * 16 + q * 2];
        float4 bb = X4[(size_t)node * 16 + q * 2 + 1];
        uint4 o;
        o.x = packbf(a.x * dd, a.y * dd);
        o.y = packbf(a.z * dd, a.w * dd);
        o.z = packbf(bb.x * dd, bb.y * dd);
        o.w = packbf(bb.z * dd, bb.w * dd);
        xnb[(size_t)node * 8 + q] = o;
    }
}

// Fused gather1 + gemm1m. Block = 256 nodes.
// Phase 1: gather aggb rows (bf16) into LDS [256][72] (pad -> 2-lane/bank reads).
// Phase 2: 4 waves x 4 tiles of 16 rows; W1 fragments in registers;
//          h1b = bf16(relu(A @ W1 + b1)) via v_mfma_f32_16x16x32_bf16.
// Layouts (guide-verified m89/m91): A row=lane&15, k=(lane>>4)*8+j;
// B col=lane&15, k=(lane>>4)*8+j; D col=lane&15, row=(lane>>4)*4+reg.
__global__ __launch_bounds__(THREADS) void k_g1fused(const int* __restrict__ offs,
                                                     const int* __restrict__ deg,
                                                     const int* __restrict__ srcs,
                                                     const float* __restrict__ dinv,
                                                     const uint4* __restrict__ xnb,
                                                     const float* __restrict__ W1,
                                                     const float* __restrict__ b1,
                                                     unsigned short* __restrict__ h1b,
                                                     int n) {
    __shared__ unsigned short As[G1ROWS][72];  // 36 KB, row stride 144 B
    const int tid = threadIdx.x;
    const int base = blockIdx.x * G1ROWS;

    // ---- phase 1: gather 256 rows into LDS (8 consecutive lanes per node) ----
    for (int t = 0; t < 8; ++t) {
        int task = t * THREADS + tid;
        int r = task >> 3;
        int node = base + r;
        if (node >= n) continue;
        int q = task & 7;
        float acc[8];
        unpack8(xnb[(size_t)node * 8 + q], acc);  // self term (pre-scaled)
        int e0 = offs[node], e1 = e0 + deg[node];
        for (int e = e0; e < e1; ++e) {
            int s = srcs[e];
            float tv[8];
            unpack8(xnb[(size_t)s * 8 + q], tv);
#pragma unroll
            for (int j = 0; j < 8; ++j) acc[j] += tv[j];
        }
        float dd = dinv[node];
        uint4 o;
        o.x = packbf(acc[0] * dd, acc[1] * dd);
        o.y = packbf(acc[2] * dd, acc[3] * dd);
        o.z = packbf(acc[4] * dd, acc[5] * dd);
        o.w = packbf(acc[6] * dd, acc[7] * dd);
        *(uint4*)&As[r][q * 8] = o;
    }

    // ---- W1 fragments + bias (registers; L2-hot) ----
    const int wave = tid >> 6;
    const int lane = tid & 63;
    const int col = lane & 15;
    const int ko = lane >> 4;  // 0..3
    bf16x8 bfr[2][8];
#pragma unroll
    for (int ks = 0; ks < 2; ++ks)
#pragma unroll
        for (int nt = 0; nt < 8; ++nt) {
            bf16x8 b;
#pragma unroll
            for (int j = 0; j < 8; ++j)
                b[j] = (short)f2bf(W1[(ks * 32 + ko * 8 + j) * 128 + nt * 16 + col]);
            bfr[ks][nt] = b;
        }
    float bias[8];
#pragma unroll
    for (int nt = 0; nt < 8; ++nt) bias[nt] = b1[nt * 16 + col];

    __syncthreads();

    // ---- phase 2: 4 tiles of 16 rows per wave ----
    for (int t = 0; t < 4; ++t) {
        int r = wave * 64 + t * 16;  // block-local row base of tile
        if (base + r >= n) break;    // tiles ascend; later tiles also out
        const unsigned short* Ar = &As[r + col][0];
        bf16x8 a0 = *(const bf16x8*)(Ar + ko * 8);
        bf16x8 a1 = *(const bf16x8*)(Ar + 32 + ko * 8);
        f32x4 acc[8];
#pragma unroll
        for (int nt = 0; nt < 8; ++nt) acc[nt] = (f32x4){0.f, 0.f, 0.f, 0.f};
#pragma unroll
        for (int nt = 0; nt < 8; ++nt) {
            acc[nt] = __builtin_amdgcn_mfma_f32_16x16x32_bf16(a0, bfr[0][nt], acc[nt], 0, 0, 0);
            acc[nt] = __builtin_amdgcn_mfma_f32_16x16x32_bf16(a1, bfr[1][nt], acc[nt], 0, 0, 0);
        }
#pragma unroll
        for (int nt = 0; nt < 8; ++nt) {
#pragma unroll
            for (int rr = 0; rr < 4; ++rr) {
                int row = base + r + ko * 4 + rr;
                if (row < n) {
                    float v = fmaxf(acc[nt][rr] + bias[nt], 0.f);
                    h1b[(size_t)row * 128 + nt * 16 + col] = f2bf(v);
                }
            }
        }
    }
}

// ts = bf16((h1b @ W2) * dinv[row]); bf16 input, fp32 accum, W2 fp32 in LDS.
__global__ __launch_bounds__(THREADS) void k_gemm2(const uint4* __restrict__ h1b4,
                                                   const float* __restrict__ W2,
                                                   const float* __restrict__ dinv,
                                                   unsigned short* __restrict__ ts, int n) {
    __shared__ float Ws[128 * 16];
    {
        float4* Ws4 = (float4*)Ws;
        const float4* W24 = (const float4*)W2;
        for (int i = threadIdx.x; i < 128 * 16 / 4; i += THREADS) Ws4[i] = W24[i];
    }
    __syncthreads();
    const int c0 = (threadIdx.x & 3) * 4;
    const int r0 = blockIdx.x * 256 + (threadIdx.x >> 2) * 4;
    if (r0 >= n) return;

    if (r0 + 3 < n) {
        const uint4* A0 = h1b4 + (size_t)r0 * 16;  // 16 uint4 (128 bf16) per row
        const uint4* A1 = A0 + 16;
        const uint4* A2 = A0 + 32;
        const uint4* A3 = A0 + 48;
        float4 acc0 = {0,0,0,0}, acc1 = {0,0,0,0}, acc2 = {0,0,0,0}, acc3 = {0,0,0,0};
#pragma unroll 4
        for (int kk = 0; kk < 16; ++kk) {
            float a0[8], a1[8], a2[8], a3[8];
            unpack8(A0[kk], a0);
            unpack8(A1[kk], a1);
            unpack8(A2[kk], a2);
            unpack8(A3[kk], a3);
#pragma unroll
            for (int j = 0; j < 8; ++j) {
                float4 w = *(const float4*)(&Ws[(kk * 8 + j) * 16 + c0]);
                acc0.x = fmaf(a0[j], w.x, acc0.x); acc0.y = fmaf(a0[j], w.y, acc0.y);
                acc0.z = fmaf(a0[j], w.z, acc0.z); acc0.w = fmaf(a0[j], w.w, acc0.w);
                acc1.x = fmaf(a1[j], w.x, acc1.x); acc1.y = fmaf(a1[j], w.y, acc1.y);
                acc1.z = fmaf(a1[j], w.z, acc1.z); acc1.w = fmaf(a1[j], w.w, acc1.w);
                acc2.x = fmaf(a2[j], w.x, acc2.x); acc2.y = fmaf(a2[j], w.y, acc2.y);
                acc2.z = fmaf(a2[j], w.z, acc2.z); acc2.w = fmaf(a2[j], w.w, acc2.w);
                acc3.x = fmaf(a3[j], w.x, acc3.x); acc3.y = fmaf(a3[j], w.y, acc3.y);
                acc3.z = fmaf(a3[j], w.z, acc3.z); acc3.w = fmaf(a3[j], w.w, acc3.w);
            }
        }
        float d0 = dinv[r0], d1 = dinv[r0 + 1], d2 = dinv[r0 + 2], d3 = dinv[r0 + 3];
        uint2 p;
        p.x = packbf(acc0.x * d0, acc0.y * d0); p.y = packbf(acc0.z * d0, acc0.w * d0);
        *(uint2*)(ts + (size_t)(r0 + 0) * 16 + c0) = p;
        p.x = packbf(acc1.x * d1, acc1.y * d1); p.y = packbf(acc1.z * d1, acc1.w * d1);
        *(uint2*)(ts + (size_t)(r0 + 1) * 16 + c0) = p;
        p.x = packbf(acc2.x * d2, acc2.y * d2); p.y = packbf(acc2.z * d2, acc2.w * d2);
        *(uint2*)(ts + (size_t)(r0 + 2) * 16 + c0) = p;
        p.x = packbf(acc3.x * d3, acc3.y * d3); p.y = packbf(acc3.z * d3, acc3.w * d3);
        *(uint2*)(ts + (size_t)(r0 + 3) * 16 + c0) = p;
    } else {
        for (int i = 0; i < 4; ++i) {
            int r = r0 + i;
            if (r >= n) break;
            const uint4* A = h1b4 + (size_t)r * 16;
            float4 acc = {0, 0, 0, 0};
            for (int kk = 0; kk < 16; ++kk) {
                float a[8];
                unpack8(A[kk], a);
#pragma unroll
                for (int j = 0; j < 8; ++j) {
                    float4 w = *(const float4*)(&Ws[(kk * 8 + j) * 16 + c0]);
                    acc.x = fmaf(a[j], w.x, acc.x); acc.y = fmaf(a[j], w.y, acc.y);
                    acc.z = fmaf(a[j], w.z, acc.z); acc.w = fmaf(a[j], w.w, acc.w);
                }
            }
            float dd = dinv[r];
            uint2 p;
            p.x = packbf(acc.x * dd, acc.y * dd);
            p.y = packbf(acc.z * dd, acc.w * dd);
            *(uint2*)(ts + (size_t)r * 16 + c0) = p;
        }
    }
}

// 2 threads/node, 8 bf16 (16B) each: h2[d] = dinv[d]*(ts[d] + sum ts[s]); fp32 out.
__global__ __launch_bounds__(THREADS) void k_gather2(const int* __restrict__ offs,
                                                     const int* __restrict__ deg,
                                                     const int* __restrict__ srcs,
                                                     const float* __restrict__ dinv,
                                                     const uint4* __restrict__ ts,
                                                     float* __restrict__ h2, int n) {
    int idx = blockIdx.x * THREADS + threadIdx.x;
    int node = idx >> 1;
    if (node >= n) return;
    int q = idx & 1;
    float acc[8];
    unpack8(ts[(size_t)node * 2 + q], acc);
    int e0 = offs[node], e1 = e0 + deg[node];
    for (int e = e0; e < e1; ++e) {
        int s = srcs[e];
        float t[8];
        unpack8(ts[(size_t)s * 2 + q], t);
#pragma unroll
        for (int j = 0; j < 8; ++j) acc[j] += t[j];
    }
    float dd = dinv[node];
    float4 o0 = {acc[0] * dd, acc[1] * dd, acc[2] * dd, acc[3] * dd};
    float4 o1 = {acc[4] * dd, acc[5] * dd, acc[6] * dd, acc[7] * dd};
    float4* O = (float4*)(h2 + (size_t)node * 16 + q * 8);
    O[0] = o0;
    O[1] = o1;
}

// One block per graph; batch sorted -> binary-search bounds, tree-reduce.
__global__ __launch_bounds__(THREADS) void k_pool(const float* __restrict__ h2,
                                                  const int* __restrict__ batch,
                                                  float* __restrict__ sums,
                                                  float* __restrict__ cnts, int n) {
    int g = blockIdx.x;
    int lo = 0, hi = n;
    while (lo < hi) { int mid = (lo + hi) >> 1; if (batch[mid] < g) lo = mid + 1; else hi = mid; }
    int s0 = lo;
    hi = n;
    while (lo < hi) { int mid = (lo + hi) >> 1; if (batch[mid] < g + 1) lo = mid + 1; else hi = mid; }
    int s1 = lo;

    int c = threadIdx.x & 15;
    int rg = threadIdx.x >> 4;
    float acc = 0.f;
    for (int i = s0 + rg; i < s1; i += 16) acc += h2[(size_t)i * 16 + c];
    __shared__ float red[THREADS];
    red[threadIdx.x] = acc;
    __syncthreads();
    for (int step = 128; step >= 16; step >>= 1) {
        if (threadIdx.x < step) red[threadIdx.x] += red[threadIdx.x + step];
        __syncthreads();
    }
    if (threadIdx.x < 16) sums[g * 16 + threadIdx.x] = red[threadIdx.x];
    if (threadIdx.x == 0) cnts[g] = (float)(s1 - s0);
}

__global__ __launch_bounds__(128) void k_final(const float* __restrict__ sums,
                                               const float* __restrict__ cnts,
                                               const float* __restrict__ b2,
                                               float* __restrict__ out) {
    int g = threadIdx.x;
    if (g >= 128) return;
    float cnt = fmaxf(cnts[g], 1.0f);
    float v[16];
    float mx = -1e30f;
#pragma unroll
    for (int c = 0; c < 16; ++c) {
        v[c] = sums[g * 16 + c] / cnt + b2[c];
        mx = fmaxf(mx, v[c]);
    }
    float se = 0.f;
#pragma unroll
    for (int c = 0; c < 16; ++c) se += expf(v[c] - mx);
    float lse = logf(se) + mx;
#pragma unroll
    for (int c = 0; c < 16; ++c) out[g * 16 + c] = v[c] - lse;
}

extern "C" void kernel_launch(void* const* d_in, const int* in_sizes, int n_in,
                              void* d_out, int out_size, void* d_ws, size_t ws_size,
                              hipStream_t stream) {
    const float* x    = (const float*)d_in[0];
    const int* edges  = (const int*)d_in[1];
    const int* batch  = (const int*)d_in[2];
    const float* W1   = (const float*)d_in[3];
    const float* b1   = (const float*)d_in[4];
    const float* W2   = (const float*)d_in[5];
    const float* b2   = (const float*)d_in[6];
    float* out        = (float*)d_out;

    const int n = in_sizes[2];
    const int E = in_sizes[1] / 2;
    const int* src = edges;
    const int* dst = edges + E;
    const int NB = (n + NPB - 1) / NPB;             // 196 <= 256
    const int npart = (E + CH - 1) / CH;            // 147

    char* ws = (char*)d_ws;
    size_t off = 0;
    auto carve = [&](size_t bytes) { char* p = ws + off; off = (off + bytes + 255) & ~(size_t)255; return p; };
    int*   bucketCursor = (int*)carve(256 * 4);
    int*   offs    = (int*)carve((size_t)n * 4);
    int*   deg     = (int*)carve((size_t)n * 4);
    int*   srcs    = (int*)carve((size_t)NB * BSTRIDE * 4);   // 6.4 MB, bucket-strided
    float* dinv    = (float*)carve((size_t)n * 4);
    uint4* xnb     = (uint4*)carve((size_t)n * 64 * 2);       // 12.8 MB bf16
    char*  aggreg  = (char*)carve((size_t)n * 64 * 2);        // ts bf16 + h2 fp32
    char*  big     = (char*)carve((size_t)n * 128 * 2);       // ebuf (9.6MB) -> h1b (25.6MB)
    float* sums    = (float*)carve(128 * 16 * 4);
    float* cnts    = (float*)carve(128 * 4);
    int2*  ebuf = (int2*)big;                       // dead before k_g1fused writes h1b
    unsigned short* h1b = (unsigned short*)big;
    unsigned short* ts = (unsigned short*)aggreg;   // [0, 3.2MB)
    float* h2 = (float*)(aggreg + (size_t)n * 16 * 4);  // [6.4MB, 12.8MB)

    auto blks = [](long long work) { return (int)((work + THREADS - 1) / THREADS); };

    hipMemsetAsync(bucketCursor, 0, 256 * 4, stream);
    k_partition  <<<npart, THREADS, 0, stream>>>(src, dst, bucketCursor, ebuf, E);
    k_bucket_csr <<<NB, THREADS, 0, stream>>>(ebuf, bucketCursor, x, offs, deg, srcs, dinv, xnb, n);

    k_g1fused <<<(n + G1ROWS - 1) / G1ROWS, THREADS, 0, stream>>>(offs, deg, srcs, dinv, xnb, W1, b1, h1b, n);
    k_gemm2   <<<(n + 255) / 256, THREADS, 0, stream>>>((const uint4*)h1b, W2, dinv, ts, n);
    k_gather2 <<<blks((long long)n * 2), THREADS, 0, stream>>>(offs, deg, srcs, dinv, (const uint4*)ts, h2, n);

    k_pool    <<<128, THREADS, 0, stream>>>(h2, batch, sums, cnts, n);
    k_final   <<<1, 128, 0, stream>>>(sums, cnts, b2, out);
}

// Round 10
// 156.889 us; speedup vs baseline: 1.4061x; 1.4061x over previous
//
#include <hip/hip_runtime.h>
#include <hip/hip_bf16.h>

// GCN via bucketed-CSR gather (no global fine-grain atomics), bf16-compressed
// gather operands, bf16-MFMA layer-1 transform (separate kernels — the fused
// gather+GEMM variant collapsed occupancy and regressed 1.4x, round 9):
//   xnb[i] = bf16(x[i]*dinv[i])
//   aggb[d] = bf16(dinv[d]*(xnb[d] + sum_{s in N(d)} xnb[s]))    (fp32 accum)
//   h1b = bf16(relu(aggb @ W1 + b1))                             (MFMA, fp32 acc)
//   ts = bf16((h1b @ W2) * dinv[row])                            (fp32 acc)
//   h2[d] = dinv[d]*(ts[d] + sum_{s in N(d)} ts[s])              (fp32 accum)
//   out = log_softmax(segment_mean(h2) + b2)
// CSR build: fixed-stride bucket regions (8192 edges/bucket, counts
// ~Poisson(6144)); partition packs (local_dst<<17)|src into ONE int per edge
// (src < 2^17, local < 2^9); per-bucket LDS counting sort emits
// offs/deg/dinv/srcs + the bf16 xnb rows for its 512 nodes.

#define THREADS 256
#define NPB 512        // nodes per bucket (shift 9)
#define BSTRIDE 8192   // fixed edge capacity per bucket region
#define CH 8192        // edges per partition block

typedef __attribute__((ext_vector_type(8))) short bf16x8;
typedef __attribute__((ext_vector_type(4))) float f32x4;

__device__ __forceinline__ float bfu_lo(unsigned int u) {
    union { unsigned int i; float f; } v; v.i = u << 16; return v.f;
}
__device__ __forceinline__ float bfu_hi(unsigned int u) {
    union { unsigned int i; float f; } v; v.i = u & 0xffff0000u; return v.f;
}
__device__ __forceinline__ unsigned short f2bf(float f) {
    union { float f; unsigned int i; } v; v.f = f;
    unsigned int r = v.i + 0x7fff + ((v.i >> 16) & 1);  // RNE
    return (unsigned short)(r >> 16);
}
__device__ __forceinline__ unsigned int packbf(float lo, float hi) {
    return (unsigned int)f2bf(lo) | ((unsigned int)f2bf(hi) << 16);
}
__device__ __forceinline__ void unpack8(uint4 u, float* f) {
    f[0] = bfu_lo(u.x); f[1] = bfu_hi(u.x);
    f[2] = bfu_lo(u.y); f[3] = bfu_hi(u.y);
    f[4] = bfu_lo(u.z); f[5] = bfu_hi(u.z);
    f[6] = bfu_lo(u.w); f[7] = bfu_hi(u.w);
}

// Partition edges into fixed-stride bucket regions of ebuf, packed
// (local_dst<<17)|src. LDS hist -> one reservation atomic per (block,bucket)
// -> LDS-cursor placement.
__global__ __launch_bounds__(THREADS) void k_partition(const int* __restrict__ src,
                                                       const int* __restrict__ dst,
                                                       int* __restrict__ bucketCursor,
                                                       unsigned int* __restrict__ ebuf, int E) {
    __shared__ int h[256];
    __shared__ int base[256];
    __shared__ int cnt[256];
    h[threadIdx.x] = 0;
    cnt[threadIdx.x] = 0;
    __syncthreads();
    int b0 = blockIdx.x * CH;
    for (int k = 0; k < CH; k += THREADS) {
        int e = b0 + k + threadIdx.x;
        if (e < E) atomicAdd(&h[dst[e] >> 9], 1);
    }
    __syncthreads();
    if (h[threadIdx.x])
        base[threadIdx.x] = threadIdx.x * BSTRIDE + atomicAdd(&bucketCursor[threadIdx.x], h[threadIdx.x]);
    __syncthreads();
    for (int k = 0; k < CH; k += THREADS) {
        int e = b0 + k + threadIdx.x;
        if (e < E) {
            int s = src[e], d = dst[e];
            int b = d >> 9;
            int i = base[b] + atomicAdd(&cnt[b], 1);
            ebuf[i] = ((unsigned int)(d & (NPB - 1)) << 17) | (unsigned int)s;
        }
    }
}

// One block per bucket: LDS counting sort -> offs/deg/dinv/srcs, then fused
// xnb emission (xnb[i] = bf16(x[i]*dinv[i])) for the bucket's 512 nodes.
__global__ __launch_bounds__(THREADS) void k_bucket_csr(const unsigned int* __restrict__ ebuf,
                                                        const int* __restrict__ bucketCursor,
                                                        const float* __restrict__ x,
                                                        int* __restrict__ offs,
                                                        int* __restrict__ deg,
                                                        int* __restrict__ srcs,
                                                        float* __restrict__ dinv,
                                                        uint4* __restrict__ xnb,
                                                        int n) {
    __shared__ int c[NPB];
    __shared__ int cur[NPB];
    __shared__ float dloc[NPB];
    __shared__ int sh[THREADS];
    int b = blockIdx.x;
    int nbase = b * NPB;
    int w0 = b * BSTRIDE;
    int cnt_b = bucketCursor[b];
    c[threadIdx.x] = 0;
    c[threadIdx.x + 256] = 0;
    __syncthreads();
    for (int i = w0 + threadIdx.x; i < w0 + cnt_b; i += THREADS)
        atomicAdd(&c[ebuf[i] >> 17], 1);
    __syncthreads();
    int c0 = c[2 * threadIdx.x], c1 = c[2 * threadIdx.x + 1];
    int s = c0 + c1;
    sh[threadIdx.x] = s;
    __syncthreads();
    for (int step = 1; step < THREADS; step <<= 1) {
        int t = (threadIdx.x >= step) ? sh[threadIdx.x - step] : 0;
        __syncthreads();
        sh[threadIdx.x] += t;
        __syncthreads();
    }
    int excl = sh[threadIdx.x] - s;
    int node0 = nbase + 2 * threadIdx.x;
    float d0 = rsqrtf((float)(c0 + 1));
    float d1 = rsqrtf((float)(c1 + 1));
    dloc[2 * threadIdx.x] = d0;
    dloc[2 * threadIdx.x + 1] = d1;
    if (node0 < n) {
        offs[node0] = w0 + excl;
        deg[node0] = c0;
        dinv[node0] = d0;
    }
    if (node0 + 1 < n) {
        offs[node0 + 1] = w0 + excl + c0;
        deg[node0 + 1] = c1;
        dinv[node0 + 1] = d1;
    }
    cur[2 * threadIdx.x] = excl;
    cur[2 * threadIdx.x + 1] = excl + c0;
    __syncthreads();
    for (int i = w0 + threadIdx.x; i < w0 + cnt_b; i += THREADS) {
        unsigned int e = ebuf[i];
        int pos = w0 + atomicAdd(&cur[e >> 17], 1);
        srcs[pos] = (int)(e & 0x1FFFFu);
    }
    // fused xnb: 8 uint4-chunks per node, 512 nodes, 16 iters per thread
    const float4* X4 = (const float4*)x;
    for (int i = threadIdx.x; i < NPB * 8; i += THREADS) {
        int ln = i >> 3;
        int node = nbase + ln;
        if (node >= n) break;  // nodes ascend with i; all later also >= n
        int q = i & 7;
        float dd = dloc[ln];
        float4 a = X4[(size_t)node * 16 + q * 2];
        float4 bb = X4[(size_t)node * 16 + q * 2 + 1];
        uint4 o;
        o.x = packbf(a.x * dd, a.y * dd);
        o.y = packbf(a.z * dd, a.w * dd);
        o.z = packbf(bb.x * dd, bb.y * dd);
        o.w = packbf(bb.z * dd, bb.w * dd);
        xnb[(size_t)node * 8 + q] = o;
    }
}

// 8 threads/node, 8 bf16 (16B) each: aggb[d] = bf16(dinv[d]*(xnb[d] + sum xnb[s])).
__global__ __launch_bounds__(THREADS) void k_gather1(const int* __restrict__ offs,
                                                     const int* __restrict__ deg,
                                                     const int* __restrict__ srcs,
                                                     const float* __restrict__ dinv,
                                                     const uint4* __restrict__ xnb,
                                                     uint4* __restrict__ aggb, int n) {
    int idx = blockIdx.x * THREADS + threadIdx.x;
    int node = idx >> 3;
    if (node >= n) return;
    int q = idx & 7;
    float acc[8];
    unpack8(xnb[(size_t)node * 8 + q], acc);  // self term (pre-scaled by dinv[d])
    int e0 = offs[node], e1 = e0 + deg[node];
    for (int e = e0; e < e1; ++e) {
        int s = srcs[e];
        float t[8];
        unpack8(xnb[(size_t)s * 8 + q], t);
#pragma unroll
        for (int j = 0; j < 8; ++j) acc[j] += t[j];
    }
    float dd = dinv[node];
    uint4 o;
    o.x = packbf(acc[0] * dd, acc[1] * dd);
    o.y = packbf(acc[2] * dd, acc[3] * dd);
    o.z = packbf(acc[4] * dd, acc[5] * dd);
    o.w = packbf(acc[6] * dd, acc[7] * dd);
    aggb[(size_t)node * 8 + q] = o;
}

// h1b = bf16(relu(aggb @ W1 + b1)) via v_mfma_f32_16x16x32_bf16.
// Wave: 16-row tile x 128 cols = 8 N-tiles x 2 K-steps = 16 MFMA; W1 fragments
// in registers; 4 tiles per wave; no LDS/barriers.
__global__ __launch_bounds__(THREADS) void k_gemm1m(const unsigned short* __restrict__ aggb,
                                                    const float* __restrict__ W1,
                                                    const float* __restrict__ b1,
                                                    unsigned short* __restrict__ h1b,
                                                    int n, int ntiles) {
    const int wave = threadIdx.x >> 6;
    const int lane = threadIdx.x & 63;
    const int col = lane & 15;
    const int ko = lane >> 4;  // 0..3

    bf16x8 bfr[2][8];
#pragma unroll
    for (int ks = 0; ks < 2; ++ks)
#pragma unroll
        for (int nt = 0; nt < 8; ++nt) {
            bf16x8 b;
#pragma unroll
            for (int j = 0; j < 8; ++j)
                b[j] = (short)f2bf(W1[(ks * 32 + ko * 8 + j) * 128 + nt * 16 + col]);
            bfr[ks][nt] = b;
        }
    float bias[8];
#pragma unroll
    for (int nt = 0; nt < 8; ++nt) bias[nt] = b1[nt * 16 + col];

    const int tile0 = (blockIdx.x * 4 + wave) * 4;  // 4 tiles per wave
    for (int t = 0; t < 4; ++t) {
        int tile = tile0 + t;
        if (tile >= ntiles) return;
        int r0 = tile * 16;
        int rowA = r0 + col;
        if (rowA >= n) rowA = n - 1;
        const bf16x8* Ap = (const bf16x8*)(aggb + (size_t)rowA * 64 + ko * 8);
        bf16x8 a0 = Ap[0];  // k in [ko*8, ko*8+8)
        bf16x8 a1 = Ap[4];  // k in [32+ko*8, 32+ko*8+8)
        f32x4 acc[8];
#pragma unroll
        for (int nt = 0; nt < 8; ++nt) acc[nt] = (f32x4){0.f, 0.f, 0.f, 0.f};
#pragma unroll
        for (int nt = 0; nt < 8; ++nt) {
            acc[nt] = __builtin_amdgcn_mfma_f32_16x16x32_bf16(a0, bfr[0][nt], acc[nt], 0, 0, 0);
            acc[nt] = __builtin_amdgcn_mfma_f32_16x16x32_bf16(a1, bfr[1][nt], acc[nt], 0, 0, 0);
        }
#pragma unroll
        for (int nt = 0; nt < 8; ++nt) {
#pragma unroll
            for (int r = 0; r < 4; ++r) {
                int row = r0 + ko * 4 + r;
                if (row < n) {
                    float v = fmaxf(acc[nt][r] + bias[nt], 0.f);
                    h1b[(size_t)row * 128 + nt * 16 + col] = f2bf(v);
                }
            }
        }
    }
}

// ts = bf16((h1b @ W2) * dinv[row]); bf16 input, fp32 accum, W2 fp32 in LDS.
__global__ __launch_bounds__(THREADS) void k_gemm2(const uint4* __restrict__ h1b4,
                                                   const float* __restrict__ W2,
                                                   const float* __restrict__ dinv,
                                                   unsigned short* __restrict__ ts, int n) {
    __shared__ float Ws[128 * 16];
    {
        float4* Ws4 = (float4*)Ws;
        const float4* W24 = (const float4*)W2;
        for (int i = threadIdx.x; i < 128 * 16 / 4; i += THREADS) Ws4[i] = W24[i];
    }
    __syncthreads();
    const int c0 = (threadIdx.x & 3) * 4;
    const int r0 = blockIdx.x * 256 + (threadIdx.x >> 2) * 4;
    if (r0 >= n) return;

    if (r0 + 3 < n) {
        const uint4* A0 = h1b4 + (size_t)r0 * 16;  // 16 uint4 (128 bf16) per row
        const uint4* A1 = A0 + 16;
        const uint4* A2 = A0 + 32;
        const uint4* A3 = A0 + 48;
        float4 acc0 = {0,0,0,0}, acc1 = {0,0,0,0}, acc2 = {0,0,0,0}, acc3 = {0,0,0,0};
#pragma unroll 4
        for (int kk = 0; kk < 16; ++kk) {
            float a0[8], a1[8], a2[8], a3[8];
            unpack8(A0[kk], a0);
            unpack8(A1[kk], a1);
            unpack8(A2[kk], a2);
            unpack8(A3[kk], a3);
#pragma unroll
            for (int j = 0; j < 8; ++j) {
                float4 w = *(const float4*)(&Ws[(kk * 8 + j) * 16 + c0]);
                acc0.x = fmaf(a0[j], w.x, acc0.x); acc0.y = fmaf(a0[j], w.y, acc0.y);
                acc0.z = fmaf(a0[j], w.z, acc0.z); acc0.w = fmaf(a0[j], w.w, acc0.w);
                acc1.x = fmaf(a1[j], w.x, acc1.x); acc1.y = fmaf(a1[j], w.y, acc1.y);
                acc1.z = fmaf(a1[j], w.z, acc1.z); acc1.w = fmaf(a1[j], w.w, acc1.w);
                acc2.x = fmaf(a2[j], w.x, acc2.x); acc2.y = fmaf(a2[j], w.y, acc2.y);
                acc2.z = fmaf(a2[j], w.z, acc2.z); acc2.w = fmaf(a2[j], w.w, acc2.w);
                acc3.x = fmaf(a3[j], w.x, acc3.x); acc3.y = fmaf(a3[j], w.y, acc3.y);
                acc3.z = fmaf(a3[j], w.z, acc3.z); acc3.w = fmaf(a3[j], w.w, acc3.w);
            }
        }
        float d0 = dinv[r0], d1 = dinv[r0 + 1], d2 = dinv[r0 + 2], d3 = dinv[r0 + 3];
        uint2 p;
        p.x = packbf(acc0.x * d0, acc0.y * d0); p.y = packbf(acc0.z * d0, acc0.w * d0);
        *(uint2*)(ts + (size_t)(r0 + 0) * 16 + c0) = p;
        p.x = packbf(acc1.x * d1, acc1.y * d1); p.y = packbf(acc1.z * d1, acc1.w * d1);
        *(uint2*)(ts + (size_t)(r0 + 1) * 16 + c0) = p;
        p.x = packbf(acc2.x * d2, acc2.y * d2); p.y = packbf(acc2.z * d2, acc2.w * d2);
        *(uint2*)(ts + (size_t)(r0 + 2) * 16 + c0) = p;
        p.x = packbf(acc3.x * d3, acc3.y * d3); p.y = packbf(acc3.z * d3, acc3.w * d3);
        *(uint2*)(ts + (size_t)(r0 + 3) * 16 + c0) = p;
    } else {
        for (int i = 0; i < 4; ++i) {
            int r = r0 + i;
            if (r >= n) break;
            const uint4* A = h1b4 + (size_t)r * 16;
            float4 acc = {0, 0, 0, 0};
            for (int kk = 0; kk < 16; ++kk) {
                float a[8];
                unpack8(A[kk], a);
#pragma unroll
                for (int j = 0; j < 8; ++j) {
                    float4 w = *(const float4*)(&Ws[(kk * 8 + j) * 16 + c0]);
                    acc.x = fmaf(a[j], w.x, acc.x); acc.y = fmaf(a[j], w.y, acc.y);
                    acc.z = fmaf(a[j], w.z, acc.z); acc.w = fmaf(a[j], w.w, acc.w);
                }
            }
            float dd = dinv[r];
            uint2 p;
            p.x = packbf(acc.x * dd, acc.y * dd);
            p.y = packbf(acc.z * dd, acc.w * dd);
            *(uint2*)(ts + (size_t)r * 16 + c0) = p;
        }
    }
}

// 2 threads/node, 8 bf16 (16B) each: h2[d] = dinv[d]*(ts[d] + sum ts[s]); fp32 out.
__global__ __launch_bounds__(THREADS) void k_gather2(const int* __restrict__ offs,
                                                     const int* __restrict__ deg,
                                                     const int* __restrict__ srcs,
                                                     const float* __restrict__ dinv,
                                                     const uint4* __restrict__ ts,
                                                     float* __restrict__ h2, int n) {
    int idx = blockIdx.x * THREADS + threadIdx.x;
    int node = idx >> 1;
    if (node >= n) return;
    int q = idx & 1;
    float acc[8];
    unpack8(ts[(size_t)node * 2 + q], acc);
    int e0 = offs[node], e1 = e0 + deg[node];
    for (int e = e0; e < e1; ++e) {
        int s = srcs[e];
        float t[8];
        unpack8(ts[(size_t)s * 2 + q], t);
#pragma unroll
        for (int j = 0; j < 8; ++j) acc[j] += t[j];
    }
    float dd = dinv[node];
    float4 o0 = {acc[0] * dd, acc[1] * dd, acc[2] * dd, acc[3] * dd};
    float4 o1 = {acc[4] * dd, acc[5] * dd, acc[6] * dd, acc[7] * dd};
    float4* O = (float4*)(h2 + (size_t)node * 16 + q * 8);
    O[0] = o0;
    O[1] = o1;
}

// One block per graph; batch sorted -> binary-search bounds, tree-reduce,
// then log_softmax of this graph's 16-channel row directly (fused final).
__global__ __launch_bounds__(THREADS) void k_poolfinal(const float* __restrict__ h2,
                                                       const int* __restrict__ batch,
                                                       const float* __restrict__ b2,
                                                       float* __restrict__ out, int n) {
    int g = blockIdx.x;
    int lo = 0, hi = n;
    while (lo < hi) { int mid = (lo + hi) >> 1; if (batch[mid] < g) lo = mid + 1; else hi = mid; }
    int s0 = lo;
    hi = n;
    while (lo < hi) { int mid = (lo + hi) >> 1; if (batch[mid] < g + 1) lo = mid + 1; else hi = mid; }
    int s1 = lo;

    int c = threadIdx.x & 15;
    int rg = threadIdx.x >> 4;
    float acc = 0.f;
    for (int i = s0 + rg; i < s1; i += 16) acc += h2[(size_t)i * 16 + c];
    __shared__ float red[THREADS];
    red[threadIdx.x] = acc;
    __syncthreads();
    for (int step = 128; step >= 16; step >>= 1) {
        if (threadIdx.x < step) red[threadIdx.x] += red[threadIdx.x + step];
        __syncthreads();
    }
    if (threadIdx.x == 0) {
        float cnt = fmaxf((float)(s1 - s0), 1.0f);
        float v[16];
        float mx = -1e30f;
#pragma unroll
        for (int k = 0; k < 16; ++k) {
            v[k] = red[k] / cnt + b2[k];
            mx = fmaxf(mx, v[k]);
        }
        float se = 0.f;
#pragma unroll
        for (int k = 0; k < 16; ++k) se += expf(v[k] - mx);
        float lse = logf(se) + mx;
#pragma unroll
        for (int k = 0; k < 16; ++k) out[g * 16 + k] = v[k] - lse;
    }
}

extern "C" void kernel_launch(void* const* d_in, const int* in_sizes, int n_in,
                              void* d_out, int out_size, void* d_ws, size_t ws_size,
                              hipStream_t stream) {
    const float* x    = (const float*)d_in[0];
    const int* edges  = (const int*)d_in[1];
    const int* batch  = (const int*)d_in[2];
    const float* W1   = (const float*)d_in[3];
    const float* b1   = (const float*)d_in[4];
    const float* W2   = (const float*)d_in[5];
    const float* b2   = (const float*)d_in[6];
    float* out        = (float*)d_out;

    const int n = in_sizes[2];
    const int E = in_sizes[1] / 2;
    const int* src = edges;
    const int* dst = edges + E;
    const int NB = (n + NPB - 1) / NPB;             // 196 <= 256
    const int npart = (E + CH - 1) / CH;            // 147
    const int ntiles = (n + 15) / 16;               // 6250

    char* ws = (char*)d_ws;
    size_t off = 0;
    auto carve = [&](size_t bytes) { char* p = ws + off; off = (off + bytes + 255) & ~(size_t)255; return p; };
    int*   bucketCursor = (int*)carve(256 * 4);
    int*   offs    = (int*)carve((size_t)n * 4);
    int*   deg     = (int*)carve((size_t)n * 4);
    int*   srcs    = (int*)carve((size_t)NB * BSTRIDE * 4);   // 6.4 MB, bucket-strided
    float* dinv    = (float*)carve((size_t)n * 4);
    uint4* xnb     = (uint4*)carve((size_t)n * 64 * 2);       // 12.8 MB bf16
    char*  aggreg  = (char*)carve((size_t)n * 64 * 2);        // aggb bf16 -> ts bf16 + h2 fp32
    char*  big     = (char*)carve((size_t)n * 128 * 2);       // ebuf (4.8MB) -> h1b (25.6MB)
    unsigned int* ebuf = (unsigned int*)big;        // dead before k_gemm1m writes h1b
    unsigned short* h1b = (unsigned short*)big;
    unsigned short* aggb = (unsigned short*)aggreg; // dead after gemm1m reads it
    unsigned short* ts = (unsigned short*)aggreg;   // [0, 3.2MB)
    float* h2 = (float*)(aggreg + (size_t)n * 16 * 4);  // [6.4MB, 12.8MB)

    auto blks = [](long long work) { return (int)((work + THREADS - 1) / THREADS); };

    hipMemsetAsync(bucketCursor, 0, 256 * 4, stream);
    k_partition  <<<npart, THREADS, 0, stream>>>(src, dst, bucketCursor, ebuf, E);
    k_bucket_csr <<<NB, THREADS, 0, stream>>>(ebuf, bucketCursor, x, offs, deg, srcs, dinv, xnb, n);

    k_gather1 <<<blks((long long)n * 8), THREADS, 0, stream>>>(offs, deg, srcs, dinv, xnb, (uint4*)aggb, n);
    k_gemm1m  <<<(ntiles + 15) / 16, THREADS, 0, stream>>>(aggb, W1, b1, h1b, n, ntiles);
    k_gemm2   <<<(n + 255) / 256, THREADS, 0, stream>>>((const uint4*)h1b, W2, dinv, ts, n);
    k_gather2 <<<blks((long long)n * 2), THREADS, 0, stream>>>(offs, deg, srcs, dinv, (const uint4*)ts, h2, n);

    k_poolfinal <<<128, THREADS, 0, stream>>>(h2, batch, b2, out, n);
}

// Round 11
// 147.428 us; speedup vs baseline: 1.4964x; 1.0642x over previous
//
#include <hip/hip_runtime.h>
#include <hip/hip_bf16.h>

// GCN via bucketed-CSR gather (no global fine-grain atomics), bf16-compressed
// gather operands, bf16-MFMA layer-1 transform:
//   xnb[i] = bf16(x[i]*dinv[i])
//   aggb[d] = bf16(dinv[d]*(xnb[d] + sum_{s in N(d)} xnb[s]))    (fp32 accum)
//   h1b = bf16(relu(aggb @ W1 + b1))                             (MFMA, fp32 acc)
//   ts = bf16((h1b @ W2) * dinv[row])                            (fp32 acc)
//   h2[d] = dinv[d]*(ts[d] + sum_{s in N(d)} ts[s])              (fp32 accum)
//   out = log_softmax(segment_mean(h2) + b2)
// CSR build: 256-node buckets (391 blocks — device-filling; round-10's 512-node
// buckets left 25% of CUs idle), fixed-stride 4096-edge regions (~Poisson(3072),
// 18-sigma headroom). Partition packs (local_dst<<17)|src in one int; bucket
// blocks stage their edges in LDS (16KB) so the counting sort touches global
// ebuf only once. Fused xnb emission per bucket.

#define THREADS 256
#define NPB 256        // nodes per bucket (shift 8)
#define BSTRIDE 4096   // fixed edge capacity per bucket region
#define CH 4096        // edges per partition block
#define NBMAX 512

typedef __attribute__((ext_vector_type(8))) short bf16x8;
typedef __attribute__((ext_vector_type(4))) float f32x4;

__device__ __forceinline__ float bfu_lo(unsigned int u) {
    union { unsigned int i; float f; } v; v.i = u << 16; return v.f;
}
__device__ __forceinline__ float bfu_hi(unsigned int u) {
    union { unsigned int i; float f; } v; v.i = u & 0xffff0000u; return v.f;
}
__device__ __forceinline__ unsigned short f2bf(float f) {
    union { float f; unsigned int i; } v; v.f = f;
    unsigned int r = v.i + 0x7fff + ((v.i >> 16) & 1);  // RNE
    return (unsigned short)(r >> 16);
}
__device__ __forceinline__ unsigned int packbf(float lo, float hi) {
    return (unsigned int)f2bf(lo) | ((unsigned int)f2bf(hi) << 16);
}
__device__ __forceinline__ void unpack8(uint4 u, float* f) {
    f[0] = bfu_lo(u.x); f[1] = bfu_hi(u.x);
    f[2] = bfu_lo(u.y); f[3] = bfu_hi(u.y);
    f[4] = bfu_lo(u.z); f[5] = bfu_hi(u.z);
    f[6] = bfu_lo(u.w); f[7] = bfu_hi(u.w);
}

// Partition edges into fixed-stride bucket regions of ebuf, packed
// (local_dst<<17)|src. LDS hist -> one reservation atomic per (block,bucket)
// -> LDS-cursor placement.
__global__ __launch_bounds__(THREADS) void k_partition(const int* __restrict__ src,
                                                       const int* __restrict__ dst,
                                                       int* __restrict__ bucketCursor,
                                                       unsigned int* __restrict__ ebuf,
                                                       int E, int NB) {
    __shared__ int h[NBMAX];
    __shared__ int base[NBMAX];
    __shared__ int cnt[NBMAX];
    for (int b = threadIdx.x; b < NBMAX; b += THREADS) { h[b] = 0; cnt[b] = 0; }
    __syncthreads();
    int b0 = blockIdx.x * CH;
    for (int k = 0; k < CH; k += THREADS) {
        int e = b0 + k + threadIdx.x;
        if (e < E) atomicAdd(&h[dst[e] >> 8], 1);
    }
    __syncthreads();
    for (int b = threadIdx.x; b < NB; b += THREADS)
        if (h[b]) base[b] = b * BSTRIDE + atomicAdd(&bucketCursor[b], h[b]);
    __syncthreads();
    for (int k = 0; k < CH; k += THREADS) {
        int e = b0 + k + threadIdx.x;
        if (e < E) {
            int s = src[e], d = dst[e];
            int b = d >> 8;
            int i = base[b] + atomicAdd(&cnt[b], 1);
            ebuf[i] = ((unsigned int)(d & (NPB - 1)) << 17) | (unsigned int)s;
        }
    }
}

// One block per bucket (256 nodes): edges staged to LDS during count pass ->
// 1-node/thread scan -> offs/deg/dinv (coalesced) -> srcs scatter from LDS via
// LDS cursors -> fused xnb emission (xnb[i] = bf16(x[i]*dinv[i])).
__global__ __launch_bounds__(THREADS) void k_bucket_csr(const unsigned int* __restrict__ ebuf,
                                                        const int* __restrict__ bucketCursor,
                                                        const float* __restrict__ x,
                                                        int* __restrict__ offs,
                                                        int* __restrict__ deg,
                                                        int* __restrict__ srcs,
                                                        float* __restrict__ dinv,
                                                        uint4* __restrict__ xnb,
                                                        int n) {
    __shared__ unsigned int eL[BSTRIDE];  // 16 KB edge staging
    __shared__ int c[NPB];
    __shared__ int cur[NPB];
    __shared__ float dloc[NPB];
    __shared__ int sh[THREADS];
    const int tid = threadIdx.x;
    const int b = blockIdx.x;
    const int nbase = b * NPB;
    const int w0 = b * BSTRIDE;
    const int cnt_b = bucketCursor[b];
    c[tid] = 0;
    __syncthreads();
    for (int i = tid; i < cnt_b; i += THREADS) {
        unsigned int e = ebuf[w0 + i];
        eL[i] = e;
        atomicAdd(&c[e >> 17], 1);
    }
    __syncthreads();
    int c0 = c[tid];
    sh[tid] = c0;
    __syncthreads();
    for (int step = 1; step < THREADS; step <<= 1) {
        int t = (tid >= step) ? sh[tid - step] : 0;
        __syncthreads();
        sh[tid] += t;
        __syncthreads();
    }
    int excl = sh[tid] - c0;  // exclusive prefix
    int node = nbase + tid;
    float dv = rsqrtf((float)(c0 + 1));
    dloc[tid] = dv;
    if (node < n) {
        offs[node] = w0 + excl;
        deg[node] = c0;
        dinv[node] = dv;
    }
    cur[tid] = excl;
    __syncthreads();
    for (int i = tid; i < cnt_b; i += THREADS) {
        unsigned int e = eL[i];
        int pos = w0 + atomicAdd(&cur[e >> 17], 1);
        srcs[pos] = (int)(e & 0x1FFFFu);
    }
    // fused xnb: 8 uint4-chunks per node, 256 nodes, 8 iters per thread
    const float4* X4 = (const float4*)x;
    for (int i = tid; i < NPB * 8; i += THREADS) {
        int ln = i >> 3;
        int node2 = nbase + ln;
        if (node2 >= n) break;  // nodes ascend with i
        int q = i & 7;
        float dd = dloc[ln];
        float4 a = X4[(size_t)node2 * 16 + q * 2];
        float4 bb = X4[(size_t)node2 * 16 + q * 2 + 1];
        uint4 o;
        o.x = packbf(a.x * dd, a.y * dd);
        o.y = packbf(a.z * dd, a.w * dd);
        o.z = packbf(bb.x * dd, bb.y * dd);
        o.w = packbf(bb.z * dd, bb.w * dd);
        xnb[(size_t)node2 * 8 + q] = o;
    }
}

// 8 threads/node, 8 bf16 (16B) each: aggb[d] = bf16(dinv[d]*(xnb[d] + sum xnb[s])).
__global__ __launch_bounds__(THREADS) void k_gather1(const int* __restrict__ offs,
                                                     const int* __restrict__ deg,
                                                     const int* __restrict__ srcs,
                                                     const float* __restrict__ dinv,
                                                     const uint4* __restrict__ xnb,
                                                     uint4* __restrict__ aggb, int n) {
    int idx = blockIdx.x * THREADS + threadIdx.x;
    int node = idx >> 3;
    if (node >= n) return;
    int q = idx & 7;
    float acc[8];
    unpack8(xnb[(size_t)node * 8 + q], acc);  // self term (pre-scaled by dinv[d])
    int e0 = offs[node], e1 = e0 + deg[node];
    for (int e = e0; e < e1; ++e) {
        int s = srcs[e];
        float t[8];
        unpack8(xnb[(size_t)s * 8 + q], t);
#pragma unroll
        for (int j = 0; j < 8; ++j) acc[j] += t[j];
    }
    float dd = dinv[node];
    uint4 o;
    o.x = packbf(acc[0] * dd, acc[1] * dd);
    o.y = packbf(acc[2] * dd, acc[3] * dd);
    o.z = packbf(acc[4] * dd, acc[5] * dd);
    o.w = packbf(acc[6] * dd, acc[7] * dd);
    aggb[(size_t)node * 8 + q] = o;
}

// h1b = bf16(relu(aggb @ W1 + b1)) via v_mfma_f32_16x16x32_bf16.
// Wave: 16-row tile x 128 cols = 8 N-tiles x 2 K-steps = 16 MFMA; W1 fragments
// in registers; 4 tiles per wave; no LDS/barriers.
__global__ __launch_bounds__(THREADS) void k_gemm1m(const unsigned short* __restrict__ aggb,
                                                    const float* __restrict__ W1,
                                                    const float* __restrict__ b1,
                                                    unsigned short* __restrict__ h1b,
                                                    int n, int ntiles) {
    const int wave = threadIdx.x >> 6;
    const int lane = threadIdx.x & 63;
    const int col = lane & 15;
    const int ko = lane >> 4;  // 0..3

    bf16x8 bfr[2][8];
#pragma unroll
    for (int ks = 0; ks < 2; ++ks)
#pragma unroll
        for (int nt = 0; nt < 8; ++nt) {
            bf16x8 b;
#pragma unroll
            for (int j = 0; j < 8; ++j)
                b[j] = (short)f2bf(W1[(ks * 32 + ko * 8 + j) * 128 + nt * 16 + col]);
            bfr[ks][nt] = b;
        }
    float bias[8];
#pragma unroll
    for (int nt = 0; nt < 8; ++nt) bias[nt] = b1[nt * 16 + col];

    const int tile0 = (blockIdx.x * 4 + wave) * 4;  // 4 tiles per wave
    for (int t = 0; t < 4; ++t) {
        int tile = tile0 + t;
        if (tile >= ntiles) return;
        int r0 = tile * 16;
        int rowA = r0 + col;
        if (rowA >= n) rowA = n - 1;
        const bf16x8* Ap = (const bf16x8*)(aggb + (size_t)rowA * 64 + ko * 8);
        bf16x8 a0 = Ap[0];  // k in [ko*8, ko*8+8)
        bf16x8 a1 = Ap[4];  // k in [32+ko*8, 32+ko*8+8)
        f32x4 acc[8];
#pragma unroll
        for (int nt = 0; nt < 8; ++nt) acc[nt] = (f32x4){0.f, 0.f, 0.f, 0.f};
#pragma unroll
        for (int nt = 0; nt < 8; ++nt) {
            acc[nt] = __builtin_amdgcn_mfma_f32_16x16x32_bf16(a0, bfr[0][nt], acc[nt], 0, 0, 0);
            acc[nt] = __builtin_amdgcn_mfma_f32_16x16x32_bf16(a1, bfr[1][nt], acc[nt], 0, 0, 0);
        }
#pragma unroll
        for (int nt = 0; nt < 8; ++nt) {
#pragma unroll
            for (int r = 0; r < 4; ++r) {
                int row = r0 + ko * 4 + r;
                if (row < n) {
                    float v = fmaxf(acc[nt][r] + bias[nt], 0.f);
                    h1b[(size_t)row * 128 + nt * 16 + col] = f2bf(v);
                }
            }
        }
    }
}

// ts = bf16((h1b @ W2) * dinv[row]); bf16 input, fp32 accum, W2 fp32 in LDS.
__global__ __launch_bounds__(THREADS) void k_gemm2(const uint4* __restrict__ h1b4,
                                                   const float* __restrict__ W2,
                                                   const float* __restrict__ dinv,
                                                   unsigned short* __restrict__ ts, int n) {
    __shared__ float Ws[128 * 16];
    {
        float4* Ws4 = (float4*)Ws;
        const float4* W24 = (const float4*)W2;
        for (int i = threadIdx.x; i < 128 * 16 / 4; i += THREADS) Ws4[i] = W24[i];
    }
    __syncthreads();
    const int c0 = (threadIdx.x & 3) * 4;
    const int r0 = blockIdx.x * 256 + (threadIdx.x >> 2) * 4;
    if (r0 >= n) return;

    if (r0 + 3 < n) {
        const uint4* A0 = h1b4 + (size_t)r0 * 16;  // 16 uint4 (128 bf16) per row
        const uint4* A1 = A0 + 16;
        const uint4* A2 = A0 + 32;
        const uint4* A3 = A0 + 48;
        float4 acc0 = {0,0,0,0}, acc1 = {0,0,0,0}, acc2 = {0,0,0,0}, acc3 = {0,0,0,0};
#pragma unroll 4
        for (int kk = 0; kk < 16; ++kk) {
            float a0[8], a1[8], a2[8], a3[8];
            unpack8(A0[kk], a0);
            unpack8(A1[kk], a1);
            unpack8(A2[kk], a2);
            unpack8(A3[kk], a3);
#pragma unroll
            for (int j = 0; j < 8; ++j) {
                float4 w = *(const float4*)(&Ws[(kk * 8 + j) * 16 + c0]);
                acc0.x = fmaf(a0[j], w.x, acc0.x); acc0.y = fmaf(a0[j], w.y, acc0.y);
                acc0.z = fmaf(a0[j], w.z, acc0.z); acc0.w = fmaf(a0[j], w.w, acc0.w);
                acc1.x = fmaf(a1[j], w.x, acc1.x); acc1.y = fmaf(a1[j], w.y, acc1.y);
                acc1.z = fmaf(a1[j], w.z, acc1.z); acc1.w = fmaf(a1[j], w.w, acc1.w);
                acc2.x = fmaf(a2[j], w.x, acc2.x); acc2.y = fmaf(a2[j], w.y, acc2.y);
                acc2.z = fmaf(a2[j], w.z, acc2.z); acc2.w = fmaf(a2[j], w.w, acc2.w);
                acc3.x = fmaf(a3[j], w.x, acc3.x); acc3.y = fmaf(a3[j], w.y, acc3.y);
                acc3.z = fmaf(a3[j], w.z, acc3.z); acc3.w = fmaf(a3[j], w.w, acc3.w);
            }
        }
        float d0 = dinv[r0], d1 = dinv[r0 + 1], d2 = dinv[r0 + 2], d3 = dinv[r0 + 3];
        uint2 p;
        p.x = packbf(acc0.x * d0, acc0.y * d0); p.y = packbf(acc0.z * d0, acc0.w * d0);
        *(uint2*)(ts + (size_t)(r0 + 0) * 16 + c0) = p;
        p.x = packbf(acc1.x * d1, acc1.y * d1); p.y = packbf(acc1.z * d1, acc1.w * d1);
        *(uint2*)(ts + (size_t)(r0 + 1) * 16 + c0) = p;
        p.x = packbf(acc2.x * d2, acc2.y * d2); p.y = packbf(acc2.z * d2, acc2.w * d2);
        *(uint2*)(ts + (size_t)(r0 + 2) * 16 + c0) = p;
        p.x = packbf(acc3.x * d3, acc3.y * d3); p.y = packbf(acc3.z * d3, acc3.w * d3);
        *(uint2*)(ts + (size_t)(r0 + 3) * 16 + c0) = p;
    } else {
        for (int i = 0; i < 4; ++i) {
            int r = r0 + i;
            if (r >= n) break;
            const uint4* A = h1b4 + (size_t)r * 16;
            float4 acc = {0, 0, 0, 0};
            for (int kk = 0; kk < 16; ++kk) {
                float a[8];
                unpack8(A[kk], a);
#pragma unroll
                for (int j = 0; j < 8; ++j) {
                    float4 w = *(const float4*)(&Ws[(kk * 8 + j) * 16 + c0]);
                    acc.x = fmaf(a[j], w.x, acc.x); acc.y = fmaf(a[j], w.y, acc.y);
                    acc.z = fmaf(a[j], w.z, acc.z); acc.w = fmaf(a[j], w.w, acc.w);
                }
            }
            float dd = dinv[r];
            uint2 p;
            p.x = packbf(acc.x * dd, acc.y * dd);
            p.y = packbf(acc.z * dd, acc.w * dd);
            *(uint2*)(ts + (size_t)r * 16 + c0) = p;
        }
    }
}

// 2 threads/node, 8 bf16 (16B) each: h2[d] = dinv[d]*(ts[d] + sum ts[s]); fp32 out.
__global__ __launch_bounds__(THREADS) void k_gather2(const int* __restrict__ offs,
                                                     const int* __restrict__ deg,
                                                     const int* __restrict__ srcs,
                                                     const float* __restrict__ dinv,
                                                     const uint4* __restrict__ ts,
                                                     float* __restrict__ h2, int n) {
    int idx = blockIdx.x * THREADS + threadIdx.x;
    int node = idx >> 1;
    if (node >= n) return;
    int q = idx & 1;
    float acc[8];
    unpack8(ts[(size_t)node * 2 + q], acc);
    int e0 = offs[node], e1 = e0 + deg[node];
    for (int e = e0; e < e1; ++e) {
        int s = srcs[e];
        float t[8];
        unpack8(ts[(size_t)s * 2 + q], t);
#pragma unroll
        for (int j = 0; j < 8; ++j) acc[j] += t[j];
    }
    float dd = dinv[node];
    float4 o0 = {acc[0] * dd, acc[1] * dd, acc[2] * dd, acc[3] * dd};
    float4 o1 = {acc[4] * dd, acc[5] * dd, acc[6] * dd, acc[7] * dd};
    float4* O = (float4*)(h2 + (size_t)node * 16 + q * 8);
    O[0] = o0;
    O[1] = o1;
}

// One block per graph; batch sorted -> binary-search bounds, tree-reduce,
// then log_softmax of this graph's 16-channel row directly (fused final).
__global__ __launch_bounds__(THREADS) void k_poolfinal(const float* __restrict__ h2,
                                                       const int* __restrict__ batch,
                                                       const float* __restrict__ b2,
                                                       float* __restrict__ out, int n) {
    int g = blockIdx.x;
    int lo = 0, hi = n;
    while (lo < hi) { int mid = (lo + hi) >> 1; if (batch[mid] < g) lo = mid + 1; else hi = mid; }
    int s0 = lo;
    hi = n;
    while (lo < hi) { int mid = (lo + hi) >> 1; if (batch[mid] < g + 1) lo = mid + 1; else hi = mid; }
    int s1 = lo;

    int c = threadIdx.x & 15;
    int rg = threadIdx.x >> 4;
    float acc = 0.f;
    for (int i = s0 + rg; i < s1; i += 16) acc += h2[(size_t)i * 16 + c];
    __shared__ float red[THREADS];
    red[threadIdx.x] = acc;
    __syncthreads();
    for (int step = 128; step >= 16; step >>= 1) {
        if (threadIdx.x < step) red[threadIdx.x] += red[threadIdx.x + step];
        __syncthreads();
    }
    if (threadIdx.x == 0) {
        float cnt = fmaxf((float)(s1 - s0), 1.0f);
        float v[16];
        float mx = -1e30f;
#pragma unroll
        for (int k = 0; k < 16; ++k) {
            v[k] = red[k] / cnt + b2[k];
            mx = fmaxf(mx, v[k]);
        }
        float se = 0.f;
#pragma unroll
        for (int k = 0; k < 16; ++k) se += expf(v[k] - mx);
        float lse = logf(se) + mx;
#pragma unroll
        for (int k = 0; k < 16; ++k) out[g * 16 + k] = v[k] - lse;
    }
}

extern "C" void kernel_launch(void* const* d_in, const int* in_sizes, int n_in,
                              void* d_out, int out_size, void* d_ws, size_t ws_size,
                              hipStream_t stream) {
    const float* x    = (const float*)d_in[0];
    const int* edges  = (const int*)d_in[1];
    const int* batch  = (const int*)d_in[2];
    const float* W1   = (const float*)d_in[3];
    const float* b1   = (const float*)d_in[4];
    const float* W2   = (const float*)d_in[5];
    const float* b2   = (const float*)d_in[6];
    float* out        = (float*)d_out;

    const int n = in_sizes[2];
    const int E = in_sizes[1] / 2;
    const int* src = edges;
    const int* dst = edges + E;
    const int NB = (n + NPB - 1) / NPB;             // 391 <= 512
    const int npart = (E + CH - 1) / CH;            // 294
    const int ntiles = (n + 15) / 16;               // 6250

    char* ws = (char*)d_ws;
    size_t off = 0;
    auto carve = [&](size_t bytes) { char* p = ws + off; off = (off + bytes + 255) & ~(size_t)255; return p; };
    int*   bucketCursor = (int*)carve(NBMAX * 4);
    int*   offs    = (int*)carve((size_t)n * 4);
    int*   deg     = (int*)carve((size_t)n * 4);
    int*   srcs    = (int*)carve((size_t)NB * BSTRIDE * 4);   // 6.4 MB, bucket-strided
    float* dinv    = (float*)carve((size_t)n * 4);
    uint4* xnb     = (uint4*)carve((size_t)n * 64 * 2);       // 12.8 MB bf16
    char*  aggreg  = (char*)carve((size_t)n * 64 * 2);        // aggb bf16 -> ts bf16 + h2 fp32
    char*  big     = (char*)carve((size_t)NB * BSTRIDE * 4 > (size_t)n * 128 * 2
                                  ? (size_t)NB * BSTRIDE * 4 : (size_t)n * 128 * 2);
    unsigned int* ebuf = (unsigned int*)big;        // dead before k_gemm1m writes h1b
    unsigned short* h1b = (unsigned short*)big;
    unsigned short* aggb = (unsigned short*)aggreg; // dead after gemm1m reads it
    unsigned short* ts = (unsigned short*)aggreg;   // [0, 3.2MB)
    float* h2 = (float*)(aggreg + (size_t)n * 16 * 4);  // [6.4MB, 12.8MB)

    auto blks = [](long long work) { return (int)((work + THREADS - 1) / THREADS); };

    hipMemsetAsync(bucketCursor, 0, NBMAX * 4, stream);
    k_partition  <<<npart, THREADS, 0, stream>>>(src, dst, bucketCursor, ebuf, E, NB);
    k_bucket_csr <<<NB, THREADS, 0, stream>>>(ebuf, bucketCursor, x, offs, deg, srcs, dinv, xnb, n);

    k_gather1 <<<blks((long long)n * 8), THREADS, 0, stream>>>(offs, deg, srcs, dinv, xnb, (uint4*)aggb, n);
    k_gemm1m  <<<(ntiles + 15) / 16, THREADS, 0, stream>>>(aggb, W1, b1, h1b, n, ntiles);
    k_gemm2   <<<(n + 255) / 256, THREADS, 0, stream>>>((const uint4*)h1b, W2, dinv, ts, n);
    k_gather2 <<<blks((long long)n * 2), THREADS, 0, stream>>>(offs, deg, srcs, dinv, (const uint4*)ts, h2, n);

    k_poolfinal <<<128, THREADS, 0, stream>>>(h2, batch, b2, out, n);
}

// Round 12
// 132.576 us; speedup vs baseline: 1.6640x; 1.1120x over previous
//
#include <hip/hip_runtime.h>
#include <hip/hip_bf16.h>

// GCN via bucketed-CSR gather (no global fine-grain atomics), bf16-compressed
// gather operands, fused two-stage MFMA transform (conv1 GEMM + conv2 GEMM in
// one kernel — h1 never touches global memory):
//   xnb[i] = bf16(x[i]*dinv[i])
//   aggb[d] = bf16(dinv[d]*(xnb[d] + sum_{s in N(d)} xnb[s]))    (fp32 accum)
//   (fused) h1 = bf16(relu(aggb @ W1 + b1))  [MFMA, D-layout]
//           -> per-wave LDS transpose ->
//           ts = bf16((h1 @ W2) * dinv[row]) [MFMA, bf16 W2]
//   h2[d] = dinv[d]*(ts[d] + sum_{s in N(d)} ts[s])              (fp32 accum)
//   out = log_softmax(segment_mean(h2) + b2)
// CSR build: 256-node buckets / 4096-edge fixed-stride regions (device-filling
// grids); partition packs (local_dst<<17)|src in one int; bucket blocks stage
// edges in LDS; fused xnb emission.
// NOTE round-9 lesson: do NOT fuse the latency-bound random gather with GEMM
// (occupancy collapse). This fusion is compute-stage + compute-stage only.

#define THREADS 256
#define NPB 256        // nodes per bucket (shift 8)
#define BSTRIDE 4096   // fixed edge capacity per bucket region
#define CH 4096        // edges per partition block
#define NBMAX 512

typedef __attribute__((ext_vector_type(8))) short bf16x8;
typedef __attribute__((ext_vector_type(4))) float f32x4;

__device__ __forceinline__ float bfu_lo(unsigned int u) {
    union { unsigned int i; float f; } v; v.i = u << 16; return v.f;
}
__device__ __forceinline__ float bfu_hi(unsigned int u) {
    union { unsigned int i; float f; } v; v.i = u & 0xffff0000u; return v.f;
}
__device__ __forceinline__ unsigned short f2bf(float f) {
    union { float f; unsigned int i; } v; v.f = f;
    unsigned int r = v.i + 0x7fff + ((v.i >> 16) & 1);  // RNE
    return (unsigned short)(r >> 16);
}
__device__ __forceinline__ unsigned int packbf(float lo, float hi) {
    return (unsigned int)f2bf(lo) | ((unsigned int)f2bf(hi) << 16);
}
__device__ __forceinline__ void unpack8(uint4 u, float* f) {
    f[0] = bfu_lo(u.x); f[1] = bfu_hi(u.x);
    f[2] = bfu_lo(u.y); f[3] = bfu_hi(u.y);
    f[4] = bfu_lo(u.z); f[5] = bfu_hi(u.z);
    f[6] = bfu_lo(u.w); f[7] = bfu_hi(u.w);
}

// Partition edges into fixed-stride bucket regions of ebuf, packed
// (local_dst<<17)|src. LDS hist -> one reservation atomic per (block,bucket)
// -> LDS-cursor placement.
__global__ __launch_bounds__(THREADS) void k_partition(const int* __restrict__ src,
                                                       const int* __restrict__ dst,
                                                       int* __restrict__ bucketCursor,
                                                       unsigned int* __restrict__ ebuf,
                                                       int E, int NB) {
    __shared__ int h[NBMAX];
    __shared__ int base[NBMAX];
    __shared__ int cnt[NBMAX];
    for (int b = threadIdx.x; b < NBMAX; b += THREADS) { h[b] = 0; cnt[b] = 0; }
    __syncthreads();
    int b0 = blockIdx.x * CH;
    for (int k = 0; k < CH; k += THREADS) {
        int e = b0 + k + threadIdx.x;
        if (e < E) atomicAdd(&h[dst[e] >> 8], 1);
    }
    __syncthreads();
    for (int b = threadIdx.x; b < NB; b += THREADS)
        if (h[b]) base[b] = b * BSTRIDE + atomicAdd(&bucketCursor[b], h[b]);
    __syncthreads();
    for (int k = 0; k < CH; k += THREADS) {
        int e = b0 + k + threadIdx.x;
        if (e < E) {
            int s = src[e], d = dst[e];
            int b = d >> 8;
            int i = base[b] + atomicAdd(&cnt[b], 1);
            ebuf[i] = ((unsigned int)(d & (NPB - 1)) << 17) | (unsigned int)s;
        }
    }
}

// One block per bucket (256 nodes): edges staged to LDS during count pass ->
// 1-node/thread scan -> offs/deg/dinv (coalesced) -> srcs scatter from LDS via
// LDS cursors -> fused xnb emission (xnb[i] = bf16(x[i]*dinv[i])).
__global__ __launch_bounds__(THREADS) void k_bucket_csr(const unsigned int* __restrict__ ebuf,
                                                        const int* __restrict__ bucketCursor,
                                                        const float* __restrict__ x,
                                                        int* __restrict__ offs,
                                                        int* __restrict__ deg,
                                                        int* __restrict__ srcs,
                                                        float* __restrict__ dinv,
                                                        uint4* __restrict__ xnb,
                                                        int n) {
    __shared__ unsigned int eL[BSTRIDE];  // 16 KB edge staging
    __shared__ int c[NPB];
    __shared__ int cur[NPB];
    __shared__ float dloc[NPB];
    __shared__ int sh[THREADS];
    const int tid = threadIdx.x;
    const int b = blockIdx.x;
    const int nbase = b * NPB;
    const int w0 = b * BSTRIDE;
    const int cnt_b = bucketCursor[b];
    c[tid] = 0;
    __syncthreads();
    for (int i = tid; i < cnt_b; i += THREADS) {
        unsigned int e = ebuf[w0 + i];
        eL[i] = e;
        atomicAdd(&c[e >> 17], 1);
    }
    __syncthreads();
    int c0 = c[tid];
    sh[tid] = c0;
    __syncthreads();
    for (int step = 1; step < THREADS; step <<= 1) {
        int t = (tid >= step) ? sh[tid - step] : 0;
        __syncthreads();
        sh[tid] += t;
        __syncthreads();
    }
    int excl = sh[tid] - c0;  // exclusive prefix
    int node = nbase + tid;
    float dv = rsqrtf((float)(c0 + 1));
    dloc[tid] = dv;
    if (node < n) {
        offs[node] = w0 + excl;
        deg[node] = c0;
        dinv[node] = dv;
    }
    cur[tid] = excl;
    __syncthreads();
    for (int i = tid; i < cnt_b; i += THREADS) {
        unsigned int e = eL[i];
        int pos = w0 + atomicAdd(&cur[e >> 17], 1);
        srcs[pos] = (int)(e & 0x1FFFFu);
    }
    // fused xnb: 8 uint4-chunks per node, 256 nodes, 8 iters per thread
    const float4* X4 = (const float4*)x;
    for (int i = tid; i < NPB * 8; i += THREADS) {
        int ln = i >> 3;
        int node2 = nbase + ln;
        if (node2 >= n) break;  // nodes ascend with i
        int q = i & 7;
        float dd = dloc[ln];
        float4 a = X4[(size_t)node2 * 16 + q * 2];
        float4 bb = X4[(size_t)node2 * 16 + q * 2 + 1];
        uint4 o;
        o.x = packbf(a.x * dd, a.y * dd);
        o.y = packbf(a.z * dd, a.w * dd);
        o.z = packbf(bb.x * dd, bb.y * dd);
        o.w = packbf(bb.z * dd, bb.w * dd);
        xnb[(size_t)node2 * 8 + q] = o;
    }
}

// 8 threads/node, 8 bf16 (16B) each: aggb[d] = bf16(dinv[d]*(xnb[d] + sum xnb[s])).
__global__ __launch_bounds__(THREADS) void k_gather1(const int* __restrict__ offs,
                                                     const int* __restrict__ deg,
                                                     const int* __restrict__ srcs,
                                                     const float* __restrict__ dinv,
                                                     const uint4* __restrict__ xnb,
                                                     uint4* __restrict__ aggb, int n) {
    int idx = blockIdx.x * THREADS + threadIdx.x;
    int node = idx >> 3;
    if (node >= n) return;
    int q = idx & 7;
    float acc[8];
    unpack8(xnb[(size_t)node * 8 + q], acc);  // self term (pre-scaled by dinv[d])
    int e0 = offs[node], e1 = e0 + deg[node];
    for (int e = e0; e < e1; ++e) {
        int s = srcs[e];
        float t[8];
        unpack8(xnb[(size_t)s * 8 + q], t);
#pragma unroll
        for (int j = 0; j < 8; ++j) acc[j] += t[j];
    }
    float dd = dinv[node];
    uint4 o;
    o.x = packbf(acc[0] * dd, acc[1] * dd);
    o.y = packbf(acc[2] * dd, acc[3] * dd);
    o.z = packbf(acc[4] * dd, acc[5] * dd);
    o.w = packbf(acc[6] * dd, acc[7] * dd);
    aggb[(size_t)node * 8 + q] = o;
}

// Fused conv1-GEMM + conv2-GEMM, all MFMA:
//   stage 1: h1_tile(16x128) = relu(aggb_tile @ W1 + b1)  (16 MFMA, D-layout)
//   bounce:  pack bf16 -> per-wave LDS [16][136] (D-layout scatter writes,
//            <=2-way; A-layout ds_read_b128, uniform 8/bank)
//   stage 2: ts_tile(16x16) = (h1_tile @ W2)*dinv  (4 MFMA, K=128, bf16 W2)
// W1/W2 fragments + biases live in registers (L2-hot loads once per wave).
// 4 waves x 4 tiles of 16 rows per block; no cross-wave LDS -> no barriers.
// Layouts (guide-verified m89/m91): A row=lane&15, k=(lane>>4)*8+j;
// B col=lane&15, k=(lane>>4)*8+j; D col=lane&15, row=(lane>>4)*4+reg.
__global__ __launch_bounds__(THREADS) void k_gemm12m(const unsigned short* __restrict__ aggb,
                                                     const float* __restrict__ W1,
                                                     const float* __restrict__ b1,
                                                     const float* __restrict__ W2,
                                                     const float* __restrict__ dinv,
                                                     unsigned short* __restrict__ ts,
                                                     int n, int ntiles) {
    __shared__ unsigned short h1L[4][16][136];  // 17 KB; per-wave [16][136], 16B-aligned rows
    const int wave = threadIdx.x >> 6;
    const int lane = threadIdx.x & 63;
    const int col = lane & 15;
    const int ko = lane >> 4;  // 0..3

    // W1 fragments (2 K-steps x 8 N-tiles) + bias
    bf16x8 bfr1[2][8];
#pragma unroll
    for (int ks = 0; ks < 2; ++ks)
#pragma unroll
        for (int nt = 0; nt < 8; ++nt) {
            bf16x8 b;
#pragma unroll
            for (int j = 0; j < 8; ++j)
                b[j] = (short)f2bf(W1[(ks * 32 + ko * 8 + j) * 128 + nt * 16 + col]);
            bfr1[ks][nt] = b;
        }
    float bias[8];
#pragma unroll
    for (int nt = 0; nt < 8; ++nt) bias[nt] = b1[nt * 16 + col];
    // W2 fragments (4 K-steps, N=16)
    bf16x8 bfr2[4];
#pragma unroll
    for (int ks = 0; ks < 4; ++ks) {
        bf16x8 b;
#pragma unroll
        for (int j = 0; j < 8; ++j)
            b[j] = (short)f2bf(W2[(ks * 32 + ko * 8 + j) * 16 + col]);
        bfr2[ks] = b;
    }

    const int tile0 = (blockIdx.x * 4 + wave) * 4;  // 4 tiles per wave
    for (int t = 0; t < 4; ++t) {
        int tile = tile0 + t;
        if (tile >= ntiles) return;
        int r0 = tile * 16;
        int rowA = r0 + col;
        if (rowA >= n) rowA = n - 1;  // duplicate last row on ragged tail
        const bf16x8* Ap = (const bf16x8*)(aggb + (size_t)rowA * 64 + ko * 8);
        bf16x8 a0 = Ap[0];  // k in [ko*8, ko*8+8)
        bf16x8 a1 = Ap[4];  // k in [32+ko*8, ...)
        f32x4 acc[8];
#pragma unroll
        for (int nt = 0; nt < 8; ++nt) acc[nt] = (f32x4){0.f, 0.f, 0.f, 0.f};
#pragma unroll
        for (int nt = 0; nt < 8; ++nt) {
            acc[nt] = __builtin_amdgcn_mfma_f32_16x16x32_bf16(a0, bfr1[0][nt], acc[nt], 0, 0, 0);
            acc[nt] = __builtin_amdgcn_mfma_f32_16x16x32_bf16(a1, bfr1[1][nt], acc[nt], 0, 0, 0);
        }
        // bias + relu + pack -> per-wave LDS (D-layout: row=ko*4+r, col=nt*16+col)
#pragma unroll
        for (int nt = 0; nt < 8; ++nt)
#pragma unroll
            for (int r = 0; r < 4; ++r)
                h1L[wave][ko * 4 + r][nt * 16 + col] = f2bf(fmaxf(acc[nt][r] + bias[nt], 0.f));
        // stage 2: A-layout reads (row=col of this lane), 4 K-steps of 32
        f32x4 acc2 = (f32x4){0.f, 0.f, 0.f, 0.f};
#pragma unroll
        for (int ks = 0; ks < 4; ++ks) {
            bf16x8 a2 = *(const bf16x8*)&h1L[wave][col][ks * 32 + ko * 8];
            acc2 = __builtin_amdgcn_mfma_f32_16x16x32_bf16(a2, bfr2[ks], acc2, 0, 0, 0);
        }
#pragma unroll
        for (int r = 0; r < 4; ++r) {
            int row = r0 + ko * 4 + r;
            if (row < n) {
                float dd = dinv[row];
                ts[(size_t)row * 16 + col] = f2bf(acc2[r] * dd);
            }
        }
    }
}

// 2 threads/node, 8 bf16 (16B) each: h2[d] = dinv[d]*(ts[d] + sum ts[s]); fp32 out.
__global__ __launch_bounds__(THREADS) void k_gather2(const int* __restrict__ offs,
                                                     const int* __restrict__ deg,
                                                     const int* __restrict__ srcs,
                                                     const float* __restrict__ dinv,
                                                     const uint4* __restrict__ ts,
                                                     float* __restrict__ h2, int n) {
    int idx = blockIdx.x * THREADS + threadIdx.x;
    int node = idx >> 1;
    if (node >= n) return;
    int q = idx & 1;
    float acc[8];
    unpack8(ts[(size_t)node * 2 + q], acc);
    int e0 = offs[node], e1 = e0 + deg[node];
    for (int e = e0; e < e1; ++e) {
        int s = srcs[e];
        float t[8];
        unpack8(ts[(size_t)s * 2 + q], t);
#pragma unroll
        for (int j = 0; j < 8; ++j) acc[j] += t[j];
    }
    float dd = dinv[node];
    float4 o0 = {acc[0] * dd, acc[1] * dd, acc[2] * dd, acc[3] * dd};
    float4 o1 = {acc[4] * dd, acc[5] * dd, acc[6] * dd, acc[7] * dd};
    float4* O = (float4*)(h2 + (size_t)node * 16 + q * 8);
    O[0] = o0;
    O[1] = o1;
}

// One block per graph; batch sorted -> binary-search bounds, tree-reduce,
// then log_softmax of this graph's 16-channel row directly (fused final).
__global__ __launch_bounds__(THREADS) void k_poolfinal(const float* __restrict__ h2,
                                                       const int* __restrict__ batch,
                                                       const float* __restrict__ b2,
                                                       float* __restrict__ out, int n) {
    int g = blockIdx.x;
    int lo = 0, hi = n;
    while (lo < hi) { int mid = (lo + hi) >> 1; if (batch[mid] < g) lo = mid + 1; else hi = mid; }
    int s0 = lo;
    hi = n;
    while (lo < hi) { int mid = (lo + hi) >> 1; if (batch[mid] < g + 1) lo = mid + 1; else hi = mid; }
    int s1 = lo;

    int c = threadIdx.x & 15;
    int rg = threadIdx.x >> 4;
    float acc = 0.f;
    for (int i = s0 + rg; i < s1; i += 16) acc += h2[(size_t)i * 16 + c];
    __shared__ float red[THREADS];
    red[threadIdx.x] = acc;
    __syncthreads();
    for (int step = 128; step >= 16; step >>= 1) {
        if (threadIdx.x < step) red[threadIdx.x] += red[threadIdx.x + step];
        __syncthreads();
    }
    if (threadIdx.x == 0) {
        float cnt = fmaxf((float)(s1 - s0), 1.0f);
        float v[16];
        float mx = -1e30f;
#pragma unroll
        for (int k = 0; k < 16; ++k) {
            v[k] = red[k] / cnt + b2[k];
            mx = fmaxf(mx, v[k]);
        }
        float se = 0.f;
#pragma unroll
        for (int k = 0; k < 16; ++k) se += expf(v[k] - mx);
        float lse = logf(se) + mx;
#pragma unroll
        for (int k = 0; k < 16; ++k) out[g * 16 + k] = v[k] - lse;
    }
}

extern "C" void kernel_launch(void* const* d_in, const int* in_sizes, int n_in,
                              void* d_out, int out_size, void* d_ws, size_t ws_size,
                              hipStream_t stream) {
    const float* x    = (const float*)d_in[0];
    const int* edges  = (const int*)d_in[1];
    const int* batch  = (const int*)d_in[2];
    const float* W1   = (const float*)d_in[3];
    const float* b1   = (const float*)d_in[4];
    const float* W2   = (const float*)d_in[5];
    const float* b2   = (const float*)d_in[6];
    float* out        = (float*)d_out;

    const int n = in_sizes[2];
    const int E = in_sizes[1] / 2;
    const int* src = edges;
    const int* dst = edges + E;
    const int NB = (n + NPB - 1) / NPB;             // 391 <= 512
    const int npart = (E + CH - 1) / CH;            // 294
    const int ntiles = (n + 15) / 16;               // 6250

    char* ws = (char*)d_ws;
    size_t off = 0;
    auto carve = [&](size_t bytes) { char* p = ws + off; off = (off + bytes + 255) & ~(size_t)255; return p; };
    int*   bucketCursor = (int*)carve(NBMAX * 4);
    int*   offs    = (int*)carve((size_t)n * 4);
    int*   deg     = (int*)carve((size_t)n * 4);
    int*   srcs    = (int*)carve((size_t)NB * BSTRIDE * 4);   // 6.4 MB, bucket-strided
    float* dinv    = (float*)carve((size_t)n * 4);
    uint4* xnb     = (uint4*)carve((size_t)n * 64 * 2);       // 12.8 MB bf16
    char*  aggreg  = (char*)carve((size_t)n * 64 * 2);        // aggb bf16; h2 fp32 at +6.4MB
    char*  big     = (char*)carve((size_t)NB * BSTRIDE * 4 > (size_t)n * 128 * 2
                                  ? (size_t)NB * BSTRIDE * 4 : (size_t)n * 128 * 2);
    unsigned int* ebuf = (unsigned int*)big;        // dead after k_bucket_csr
    unsigned short* ts = (unsigned short*)big;      // 3.2 MB, lives in big (no aggb overlap)
    unsigned short* aggb = (unsigned short*)aggreg; // read by k_gemm12m
    float* h2 = (float*)(aggreg + (size_t)n * 16 * 4);  // [6.4MB, 12.8MB) — clear of aggb by then

    auto blks = [](long long work) { return (int)((work + THREADS - 1) / THREADS); };

    hipMemsetAsync(bucketCursor, 0, NBMAX * 4, stream);
    k_partition  <<<npart, THREADS, 0, stream>>>(src, dst, bucketCursor, ebuf, E, NB);
    k_bucket_csr <<<NB, THREADS, 0, stream>>>(ebuf, bucketCursor, x, offs, deg, srcs, dinv, xnb, n);

    k_gather1 <<<blks((long long)n * 8), THREADS, 0, stream>>>(offs, deg, srcs, dinv, xnb, (uint4*)aggb, n);
    k_gemm12m <<<(ntiles + 15) / 16, THREADS, 0, stream>>>(aggb, W1, b1, W2, dinv, ts, n, ntiles);
    k_gather2 <<<blks((long long)n * 2), THREADS, 0, stream>>>(offs, deg, srcs, dinv, (const uint4*)ts, h2, n);

    k_poolfinal <<<128, THREADS, 0, stream>>>(h2, batch, b2, out, n);
}

// Round 13
// 129.020 us; speedup vs baseline: 1.7099x; 1.0276x over previous
//
#include <hip/hip_runtime.h>
#include <hip/hip_bf16.h>

// GCN via bucketed-CSR gather (no global fine-grain atomics), bf16-compressed
// gather operands, fused two-stage MFMA transform, fused gather2+pool:
//   xnb[i] = bf16(x[i]*dinv[i])
//   aggb[d] = bf16(dinv[d]*(xnb[d] + sum_{s in N(d)} xnb[s]))    (fp32 accum)
//   (fused) h1 = bf16(relu(aggb @ W1 + b1)) -> per-wave LDS ->
//           ts = bf16((h1 @ W2) * dinv[row])                     (MFMA both)
//   (fused) h2[d] = dinv[d]*(ts[d] + sum ts[s]) accumulated straight into
//           per-graph sums (LDS table + sparse global atomics; h2 never
//           touches global memory)
//   out = log_softmax(sums/cnt + b2)
// CSR build: 256-node buckets / 4096-edge fixed-stride regions; partition
// stages dst in LDS (single global read) and packs (local_dst<<17)|src;
// bucket blocks stage edges in LDS; fused xnb emission.
// Round-9 lesson kept: never fuse the latency-bound random gather with the
// occupancy-sensitive MFMA kernel.

#define THREADS 256
#define NPB 256        // nodes per bucket (shift 8)
#define BSTRIDE 4096   // fixed edge capacity per bucket region
#define CH 4096        // edges per partition block
#define NBMAX 512
#define NGRAPH 128     // graphs (out_size/16); LDS table sized for this

typedef __attribute__((ext_vector_type(8))) short bf16x8;
typedef __attribute__((ext_vector_type(4))) float f32x4;

__device__ __forceinline__ float bfu_lo(unsigned int u) {
    union { unsigned int i; float f; } v; v.i = u << 16; return v.f;
}
__device__ __forceinline__ float bfu_hi(unsigned int u) {
    union { unsigned int i; float f; } v; v.i = u & 0xffff0000u; return v.f;
}
__device__ __forceinline__ unsigned short f2bf(float f) {
    union { float f; unsigned int i; } v; v.f = f;
    unsigned int r = v.i + 0x7fff + ((v.i >> 16) & 1);  // RNE
    return (unsigned short)(r >> 16);
}
__device__ __forceinline__ unsigned int packbf(float lo, float hi) {
    return (unsigned int)f2bf(lo) | ((unsigned int)f2bf(hi) << 16);
}
__device__ __forceinline__ void unpack8(uint4 u, float* f) {
    f[0] = bfu_lo(u.x); f[1] = bfu_hi(u.x);
    f[2] = bfu_lo(u.y); f[3] = bfu_hi(u.y);
    f[4] = bfu_lo(u.z); f[5] = bfu_hi(u.z);
    f[6] = bfu_lo(u.w); f[7] = bfu_hi(u.w);
}

// Partition edges into fixed-stride bucket regions of ebuf, packed
// (local_dst<<17)|src. dst staged in LDS during the hist pass so global dst
// is read exactly once. One reservation atomic per (block,bucket).
__global__ __launch_bounds__(THREADS) void k_partition(const int* __restrict__ src,
                                                       const int* __restrict__ dst,
                                                       int* __restrict__ bucketCursor,
                                                       unsigned int* __restrict__ ebuf,
                                                       int E, int NB) {
    __shared__ int h[NBMAX];
    __shared__ int base[NBMAX];
    __shared__ int cnt[NBMAX];
    __shared__ int dL[CH];  // 16 KB staged dst
    for (int b = threadIdx.x; b < NBMAX; b += THREADS) { h[b] = 0; cnt[b] = 0; }
    __syncthreads();
    int b0 = blockIdx.x * CH;
    for (int k = 0; k < CH; k += THREADS) {
        int e = b0 + k + threadIdx.x;
        if (e < E) {
            int d = dst[e];
            dL[k + threadIdx.x] = d;
            atomicAdd(&h[d >> 8], 1);
        }
    }
    __syncthreads();
    for (int b = threadIdx.x; b < NB; b += THREADS)
        if (h[b]) base[b] = b * BSTRIDE + atomicAdd(&bucketCursor[b], h[b]);
    __syncthreads();
    for (int k = 0; k < CH; k += THREADS) {
        int e = b0 + k + threadIdx.x;
        if (e < E) {
            int s = src[e];
            int d = dL[k + threadIdx.x];
            int b = d >> 8;
            int i = base[b] + atomicAdd(&cnt[b], 1);
            ebuf[i] = ((unsigned int)(d & (NPB - 1)) << 17) | (unsigned int)s;
        }
    }
}

// One block per bucket (256 nodes): edges staged to LDS during count pass ->
// 1-node/thread scan -> offs/deg/dinv (coalesced) -> srcs scatter from LDS via
// LDS cursors -> fused xnb emission (xnb[i] = bf16(x[i]*dinv[i])).
__global__ __launch_bounds__(THREADS) void k_bucket_csr(const unsigned int* __restrict__ ebuf,
                                                        const int* __restrict__ bucketCursor,
                                                        const float* __restrict__ x,
                                                        int* __restrict__ offs,
                                                        int* __restrict__ deg,
                                                        int* __restrict__ srcs,
                                                        float* __restrict__ dinv,
                                                        uint4* __restrict__ xnb,
                                                        int n) {
    __shared__ unsigned int eL[BSTRIDE];  // 16 KB edge staging
    __shared__ int c[NPB];
    __shared__ int cur[NPB];
    __shared__ float dloc[NPB];
    __shared__ int sh[THREADS];
    const int tid = threadIdx.x;
    const int b = blockIdx.x;
    const int nbase = b * NPB;
    const int w0 = b * BSTRIDE;
    const int cnt_b = bucketCursor[b];
    c[tid] = 0;
    __syncthreads();
    for (int i = tid; i < cnt_b; i += THREADS) {
        unsigned int e = ebuf[w0 + i];
        eL[i] = e;
        atomicAdd(&c[e >> 17], 1);
    }
    __syncthreads();
    int c0 = c[tid];
    sh[tid] = c0;
    __syncthreads();
    for (int step = 1; step < THREADS; step <<= 1) {
        int t = (tid >= step) ? sh[tid - step] : 0;
        __syncthreads();
        sh[tid] += t;
        __syncthreads();
    }
    int excl = sh[tid] - c0;  // exclusive prefix
    int node = nbase + tid;
    float dv = rsqrtf((float)(c0 + 1));
    dloc[tid] = dv;
    if (node < n) {
        offs[node] = w0 + excl;
        deg[node] = c0;
        dinv[node] = dv;
    }
    cur[tid] = excl;
    __syncthreads();
    for (int i = tid; i < cnt_b; i += THREADS) {
        unsigned int e = eL[i];
        int pos = w0 + atomicAdd(&cur[e >> 17], 1);
        srcs[pos] = (int)(e & 0x1FFFFu);
    }
    // fused xnb: 8 uint4-chunks per node, 256 nodes, 8 iters per thread
    const float4* X4 = (const float4*)x;
    for (int i = tid; i < NPB * 8; i += THREADS) {
        int ln = i >> 3;
        int node2 = nbase + ln;
        if (node2 >= n) break;  // nodes ascend with i
        int q = i & 7;
        float dd = dloc[ln];
        float4 a = X4[(size_t)node2 * 16 + q * 2];
        float4 bb = X4[(size_t)node2 * 16 + q * 2 + 1];
        uint4 o;
        o.x = packbf(a.x * dd, a.y * dd);
        o.y = packbf(a.z * dd, a.w * dd);
        o.z = packbf(bb.x * dd, bb.y * dd);
        o.w = packbf(bb.z * dd, bb.w * dd);
        xnb[(size_t)node2 * 8 + q] = o;
    }
}

// 8 threads/node, 8 bf16 (16B) each: aggb[d] = bf16(dinv[d]*(xnb[d] + sum xnb[s])).
__global__ __launch_bounds__(THREADS) void k_gather1(const int* __restrict__ offs,
                                                     const int* __restrict__ deg,
                                                     const int* __restrict__ srcs,
                                                     const float* __restrict__ dinv,
                                                     const uint4* __restrict__ xnb,
                                                     uint4* __restrict__ aggb, int n) {
    int idx = blockIdx.x * THREADS + threadIdx.x;
    int node = idx >> 3;
    if (node >= n) return;
    int q = idx & 7;
    float acc[8];
    unpack8(xnb[(size_t)node * 8 + q], acc);  // self term (pre-scaled by dinv[d])
    int e0 = offs[node], e1 = e0 + deg[node];
    for (int e = e0; e < e1; ++e) {
        int s = srcs[e];
        float t[8];
        unpack8(xnb[(size_t)s * 8 + q], t);
#pragma unroll
        for (int j = 0; j < 8; ++j) acc[j] += t[j];
    }
    float dd = dinv[node];
    uint4 o;
    o.x = packbf(acc[0] * dd, acc[1] * dd);
    o.y = packbf(acc[2] * dd, acc[3] * dd);
    o.z = packbf(acc[4] * dd, acc[5] * dd);
    o.w = packbf(acc[6] * dd, acc[7] * dd);
    aggb[(size_t)node * 8 + q] = o;
}

// Fused conv1-GEMM + conv2-GEMM, all MFMA (h1 never leaves the CU):
//   stage 1: h1_tile(16x128) = relu(aggb_tile @ W1 + b1)  (16 MFMA, D-layout)
//   bounce:  pack bf16 -> per-wave LDS [16][136] -> A-layout ds_read_b128
//   stage 2: ts_tile(16x16) = (h1_tile @ W2)*dinv  (4 MFMA, K=128, bf16 W2)
// W1/W2 fragments + biases in registers; 4 waves x 4 tiles; no barriers.
// Layouts (guide-verified m89/m91): A row=lane&15, k=(lane>>4)*8+j;
// B col=lane&15, k=(lane>>4)*8+j; D col=lane&15, row=(lane>>4)*4+reg.
__global__ __launch_bounds__(THREADS) void k_gemm12m(const unsigned short* __restrict__ aggb,
                                                     const float* __restrict__ W1,
                                                     const float* __restrict__ b1,
                                                     const float* __restrict__ W2,
                                                     const float* __restrict__ dinv,
                                                     unsigned short* __restrict__ ts,
                                                     int n, int ntiles) {
    __shared__ unsigned short h1L[4][16][136];  // 17 KB; per-wave, 16B-aligned rows
    const int wave = threadIdx.x >> 6;
    const int lane = threadIdx.x & 63;
    const int col = lane & 15;
    const int ko = lane >> 4;  // 0..3

    bf16x8 bfr1[2][8];
#pragma unroll
    for (int ks = 0; ks < 2; ++ks)
#pragma unroll
        for (int nt = 0; nt < 8; ++nt) {
            bf16x8 b;
#pragma unroll
            for (int j = 0; j < 8; ++j)
                b[j] = (short)f2bf(W1[(ks * 32 + ko * 8 + j) * 128 + nt * 16 + col]);
            bfr1[ks][nt] = b;
        }
    float bias[8];
#pragma unroll
    for (int nt = 0; nt < 8; ++nt) bias[nt] = b1[nt * 16 + col];
    bf16x8 bfr2[4];
#pragma unroll
    for (int ks = 0; ks < 4; ++ks) {
        bf16x8 b;
#pragma unroll
        for (int j = 0; j < 8; ++j)
            b[j] = (short)f2bf(W2[(ks * 32 + ko * 8 + j) * 16 + col]);
        bfr2[ks] = b;
    }

    const int tile0 = (blockIdx.x * 4 + wave) * 4;  // 4 tiles per wave
    for (int t = 0; t < 4; ++t) {
        int tile = tile0 + t;
        if (tile >= ntiles) return;
        int r0 = tile * 16;
        int rowA = r0 + col;
        if (rowA >= n) rowA = n - 1;  // duplicate last row on ragged tail
        const bf16x8* Ap = (const bf16x8*)(aggb + (size_t)rowA * 64 + ko * 8);
        bf16x8 a0 = Ap[0];
        bf16x8 a1 = Ap[4];
        f32x4 acc[8];
#pragma unroll
        for (int nt = 0; nt < 8; ++nt) acc[nt] = (f32x4){0.f, 0.f, 0.f, 0.f};
#pragma unroll
        for (int nt = 0; nt < 8; ++nt) {
            acc[nt] = __builtin_amdgcn_mfma_f32_16x16x32_bf16(a0, bfr1[0][nt], acc[nt], 0, 0, 0);
            acc[nt] = __builtin_amdgcn_mfma_f32_16x16x32_bf16(a1, bfr1[1][nt], acc[nt], 0, 0, 0);
        }
#pragma unroll
        for (int nt = 0; nt < 8; ++nt)
#pragma unroll
            for (int r = 0; r < 4; ++r)
                h1L[wave][ko * 4 + r][nt * 16 + col] = f2bf(fmaxf(acc[nt][r] + bias[nt], 0.f));
        f32x4 acc2 = (f32x4){0.f, 0.f, 0.f, 0.f};
#pragma unroll
        for (int ks = 0; ks < 4; ++ks) {
            bf16x8 a2 = *(const bf16x8*)&h1L[wave][col][ks * 32 + ko * 8];
            acc2 = __builtin_amdgcn_mfma_f32_16x16x32_bf16(a2, bfr2[ks], acc2, 0, 0, 0);
        }
#pragma unroll
        for (int r = 0; r < 4; ++r) {
            int row = r0 + ko * 4 + r;
            if (row < n) {
                float dd = dinv[row];
                ts[(size_t)row * 16 + col] = f2bf(acc2[r] * dd);
            }
        }
    }
}

// Fused gather2 + mean-pool partial sums. 2 threads/node, 8 bf16 each:
// h2row = dinv[d]*(ts[d] + sum ts[s]) accumulated into a per-block LDS
// [NGRAPH][16] table (blocks span 1-3 graphs; LDS f32 atomics), then only
// nonzero entries flushed with global atomics (~32/block). h2 never hits
// global memory.
__global__ __launch_bounds__(THREADS) void k_gatherpool(const int* __restrict__ offs,
                                                        const int* __restrict__ deg,
                                                        const int* __restrict__ srcs,
                                                        const float* __restrict__ dinv,
                                                        const uint4* __restrict__ ts,
                                                        const int* __restrict__ batch,
                                                        float* __restrict__ sums, int n) {
    __shared__ float gsum[NGRAPH * 16];  // 8 KB
    const int tid = threadIdx.x;
    for (int i = tid; i < NGRAPH * 16; i += THREADS) gsum[i] = 0.f;
    __syncthreads();
    int idx = blockIdx.x * THREADS + tid;
    int node = idx >> 1;
    if (node < n) {
        int q = idx & 1;
        float acc[8];
        unpack8(ts[(size_t)node * 2 + q], acc);
        int e0 = offs[node], e1 = e0 + deg[node];
        for (int e = e0; e < e1; ++e) {
            int s = srcs[e];
            float t[8];
            unpack8(ts[(size_t)s * 2 + q], t);
#pragma unroll
            for (int j = 0; j < 8; ++j) acc[j] += t[j];
        }
        float dd = dinv[node];
        int g = batch[node];
        float* row = &gsum[g * 16 + q * 8];
#pragma unroll
        for (int j = 0; j < 8; ++j) atomicAdd(&row[j], acc[j] * dd);
    }
    __syncthreads();
    for (int i = tid; i < NGRAPH * 16; i += THREADS) {
        float v = gsum[i];
        if (v != 0.f) atomicAdd(&sums[i], v);
    }
}

// One tiny block: per-graph count (binary search over sorted batch), mean,
// bias, log_softmax.
__global__ __launch_bounds__(NGRAPH) void k_final(const float* __restrict__ sums,
                                                  const int* __restrict__ batch,
                                                  const float* __restrict__ b2,
                                                  float* __restrict__ out, int n) {
    int g = threadIdx.x;
    int lo = 0, hi = n;
    while (lo < hi) { int mid = (lo + hi) >> 1; if (batch[mid] < g) lo = mid + 1; else hi = mid; }
    int s0 = lo;
    hi = n;
    while (lo < hi) { int mid = (lo + hi) >> 1; if (batch[mid] < g + 1) lo = mid + 1; else hi = mid; }
    int s1 = lo;
    float cnt = fmaxf((float)(s1 - s0), 1.0f);
    float v[16];
    float mx = -1e30f;
#pragma unroll
    for (int c = 0; c < 16; ++c) {
        v[c] = sums[g * 16 + c] / cnt + b2[c];
        mx = fmaxf(mx, v[c]);
    }
    float se = 0.f;
#pragma unroll
    for (int c = 0; c < 16; ++c) se += expf(v[c] - mx);
    float lse = logf(se) + mx;
#pragma unroll
    for (int c = 0; c < 16; ++c) out[g * 16 + c] = v[c] - lse;
}

extern "C" void kernel_launch(void* const* d_in, const int* in_sizes, int n_in,
                              void* d_out, int out_size, void* d_ws, size_t ws_size,
                              hipStream_t stream) {
    const float* x    = (const float*)d_in[0];
    const int* edges  = (const int*)d_in[1];
    const int* batch  = (const int*)d_in[2];
    const float* W1   = (const float*)d_in[3];
    const float* b1   = (const float*)d_in[4];
    const float* W2   = (const float*)d_in[5];
    const float* b2   = (const float*)d_in[6];
    float* out        = (float*)d_out;

    const int n = in_sizes[2];
    const int E = in_sizes[1] / 2;
    const int* src = edges;
    const int* dst = edges + E;
    const int NB = (n + NPB - 1) / NPB;             // 391 <= 512
    const int npart = (E + CH - 1) / CH;            // 294
    const int ntiles = (n + 15) / 16;               // 6250

    char* ws = (char*)d_ws;
    size_t off = 0;
    auto carve = [&](size_t bytes) { char* p = ws + off; off = (off + bytes + 255) & ~(size_t)255; return p; };
    int*   bucketCursor = (int*)carve(NBMAX * 4);             // zeroed by memset below
    float* sums    = (float*)carve(NGRAPH * 16 * 4);          // zeroed by same memset (contiguous)
    int*   offs    = (int*)carve((size_t)n * 4);
    int*   deg     = (int*)carve((size_t)n * 4);
    int*   srcs    = (int*)carve((size_t)NB * BSTRIDE * 4);   // 6.4 MB, bucket-strided
    float* dinv    = (float*)carve((size_t)n * 4);
    uint4* xnb     = (uint4*)carve((size_t)n * 64 * 2);       // 12.8 MB bf16
    char*  aggreg  = (char*)carve((size_t)n * 64 * 2);        // aggb bf16
    char*  big     = (char*)carve((size_t)NB * BSTRIDE * 4 > (size_t)n * 128 * 2
                                  ? (size_t)NB * BSTRIDE * 4 : (size_t)n * 128 * 2);
    unsigned int* ebuf = (unsigned int*)big;        // dead after k_bucket_csr
    unsigned short* ts = (unsigned short*)big;      // 3.2 MB, reuses big after ebuf dies
    unsigned short* aggb = (unsigned short*)aggreg;

    auto blks = [](long long work) { return (int)((work + THREADS - 1) / THREADS); };

    hipMemsetAsync(bucketCursor, 0, NBMAX * 4 + NGRAPH * 16 * 4, stream);
    k_partition  <<<npart, THREADS, 0, stream>>>(src, dst, bucketCursor, ebuf, E, NB);
    k_bucket_csr <<<NB, THREADS, 0, stream>>>(ebuf, bucketCursor, x, offs, deg, srcs, dinv, xnb, n);

    k_gather1 <<<blks((long long)n * 8), THREADS, 0, stream>>>(offs, deg, srcs, dinv, xnb, (uint4*)aggb, n);
    k_gemm12m <<<(ntiles + 15) / 16, THREADS, 0, stream>>>(aggb, W1, b1, W2, dinv, ts, n, ntiles);

    k_gatherpool <<<blks((long long)n * 2), THREADS, 0, stream>>>(offs, deg, srcs, dinv,
                                                                  (const uint4*)ts, batch, sums, n);
    k_final <<<1, NGRAPH, 0, stream>>>(sums, batch, b2, out, n);
}